// Round 9
// baseline (219.744 us; speedup 1.0000x reference)
//
#include <hip/hip_runtime.h>
#include <hip/hip_bf16.h>

// PhaseSynchronizedAttention: B=2 S=2048 D=1024 H=16 DK=64, fp32 in/out.
// Round 9: k_attn K/V LDS -> [64][64] + XOR swizzle (T2) for conflict-free
// b128; exp2 path (log2e folded into Q scale, -12*log2e folded into QK^T
// accumulator init). GEMMs unchanged except the Q-proj scale constant.

typedef short bf16x8 __attribute__((ext_vector_type(8)));
typedef float f32x4 __attribute__((ext_vector_type(4)));
typedef unsigned short u16;
typedef unsigned short u16x8 __attribute__((ext_vector_type(8)));
typedef unsigned short u16x4 __attribute__((ext_vector_type(4)));

static __device__ __forceinline__ u16 f2bf(float x) {
    __hip_bfloat16 b = __float2bfloat16(x);
    return *reinterpret_cast<u16*>(&b);
}
static __device__ __forceinline__ float bf2f(u16 u) {
    __hip_bfloat16 b = *reinterpret_cast<__hip_bfloat16*>(&u);
    return __bfloat162float(b);
}
static __device__ __forceinline__ void split2(float x, u16& hi, u16& lo) {
    hi = f2bf(x);
    lo = f2bf(x - bf2f(hi));
}
static __device__ __forceinline__ bf16x8 g8(const u16* p) {
    return *reinterpret_cast<const bf16x8*>(p);
}
static __device__ __forceinline__ float fast_exp2(float x) {
#if __has_builtin(__builtin_amdgcn_exp2f)
    return __builtin_amdgcn_exp2f(x);
#else
    return __expf(0.6931471805599453f * x);
#endif
}

// ---------------- split fp32 -> bf16 hi/lo (fused: q,k,v) ----------------
__global__ void k_splitX(const float* __restrict__ q, const float* __restrict__ k,
                         const float* __restrict__ v,
                         u16* __restrict__ qh, u16* __restrict__ ql,
                         u16* __restrict__ kh, u16* __restrict__ kl,
                         u16* __restrict__ vh, u16* __restrict__ vl) {
    const int i = blockIdx.x * 256 + threadIdx.x;  // grid.x = 4096, n4 = 1048576
    const float* s;
    u16 *H, *L;
    if (blockIdx.y == 0) { s = q; H = qh; L = ql; }
    else if (blockIdx.y == 1) { s = k; H = kh; L = kl; }
    else { s = v; H = vh; L = vl; }
    float4 val = reinterpret_cast<const float4*>(s)[i];
    u16x4 h, l;
    u16 th, tl2;
    split2(val.x, th, tl2); h[0] = th; l[0] = tl2;
    split2(val.y, th, tl2); h[1] = th; l[1] = tl2;
    split2(val.z, th, tl2); h[2] = th; l[2] = tl2;
    split2(val.w, th, tl2); h[3] = th; l[3] = tl2;
    reinterpret_cast<u16x4*>(H)[i] = h;
    reinterpret_cast<u16x4*>(L)[i] = l;
}

// ---------------- split hi-only (fused: Wq,Wk,Wv,Wo) ----------------
__global__ void k_splitW(const float* __restrict__ w0, const float* __restrict__ w1,
                         const float* __restrict__ w2, const float* __restrict__ w3,
                         u16* __restrict__ h0, u16* __restrict__ h1,
                         u16* __restrict__ h2, u16* __restrict__ h3) {
    const int i = blockIdx.x * 256 + threadIdx.x;  // grid.x = 1024, n4 = 262144
    const float* s;
    u16* H;
    if (blockIdx.y == 0) { s = w0; H = h0; }
    else if (blockIdx.y == 1) { s = w1; H = h1; }
    else if (blockIdx.y == 2) { s = w2; H = h2; }
    else { s = w3; H = h3; }
    float4 val = reinterpret_cast<const float4*>(s)[i];
    u16x4 h;
    h[0] = f2bf(val.x);
    h[1] = f2bf(val.y);
    h[2] = f2bf(val.z);
    h[3] = f2bf(val.w);
    reinterpret_cast<u16x4*>(H)[i] = h;
}

// ---------------- unified GEMM: C[M,1024] = (Ah+Al) @ Bh^T + bias ---------
// z: 0=Q-proj(rotate, scale incl. log2e, split out), 1=K-proj(rotate,hi out),
// 2=V-proj(fp32 out), 3=out-proj(fp32 out). XCD swizzle.
#define LDP 40  // padded LDS row in elems (80 B)
__global__ __launch_bounds__(256) void k_gemm(
    const u16* __restrict__ qh, const u16* __restrict__ ql,
    const u16* __restrict__ kh, const u16* __restrict__ kl,
    const u16* __restrict__ vh, const u16* __restrict__ vl,
    const u16* __restrict__ aoh, const u16* __restrict__ aol,
    const u16* __restrict__ Wqh, const u16* __restrict__ Wkh,
    const u16* __restrict__ Wvh, const u16* __restrict__ Woh,
    const float* __restrict__ bq, const float* __restrict__ bk,
    const float* __restrict__ bv_, const float* __restrict__ bo,
    const float* __restrict__ phase,
    u16* __restrict__ Qrh, u16* __restrict__ Qrl,
    u16* __restrict__ Krh,
    float* __restrict__ Vp, float* __restrict__ outp, int zoff) {
    __shared__ __attribute__((aligned(16))) u16 sAh[128 * LDP];
    __shared__ __attribute__((aligned(16))) u16 sAl[128 * LDP];
    __shared__ __attribute__((aligned(16))) u16 sBh[128 * LDP];

    const int z = blockIdx.z + zoff;
    const u16 *Ah, *Al, *Bh;
    const float* bias;
    if (z == 0) { Ah = qh; Al = ql; Bh = Wqh; bias = bq; }
    else if (z == 1) { Ah = kh; Al = kl; Bh = Wkh; bias = bk; }
    else if (z == 2) { Ah = vh; Al = vl; Bh = Wvh; bias = bv_; }
    else { Ah = aoh; Al = aol; Bh = Woh; bias = bo; }

    // XCD-aware tile remap (HW: xcd = flat_wg % 8)
    const int flat = blockIdx.y * 8 + blockIdx.x;           // 0..255
    const int tau = (flat & 7) * 32 + (flat >> 3);          // bijective
    const int bx = tau & 7, by = tau >> 3;

    const int t = threadIdx.x;
    const int l = t & 63, w = t >> 6;
    const int wr = w >> 1, wc = w & 1;
    const int m0 = by * 128, n0 = bx * 128;

    const int srow = t >> 2;
    const int scol = (t & 3) * 8;
    const u16* pA0h = Ah + (size_t)(m0 + srow) * 1024 + scol;
    const u16* pA1h = Ah + (size_t)(m0 + 64 + srow) * 1024 + scol;
    const u16* pA0l = Al + (size_t)(m0 + srow) * 1024 + scol;
    const u16* pA1l = Al + (size_t)(m0 + 64 + srow) * 1024 + scol;
    const u16* pB0h = Bh + (size_t)(n0 + srow) * 1024 + scol;
    const u16* pB1h = Bh + (size_t)(n0 + 64 + srow) * 1024 + scol;
    const int so0 = srow * LDP + scol;
    const int so1 = (srow + 64) * LDP + scol;

    bf16x8 rA0h, rA1h, rA0l, rA1l, rB0h, rB1h;
    auto load_tiles = [&](int kk) {
        const int ko = kk * 32;
        rA0h = g8(pA0h + ko); rA1h = g8(pA1h + ko);
        rA0l = g8(pA0l + ko); rA1l = g8(pA1l + ko);
        rB0h = g8(pB0h + ko); rB1h = g8(pB1h + ko);
    };

    f32x4 acc[4][4];
#pragma unroll
    for (int m = 0; m < 4; ++m)
#pragma unroll
        for (int n = 0; n < 4; ++n) acc[m][n] = (f32x4){0.f, 0.f, 0.f, 0.f};

    const int fr = l & 15;
    const int fk = (l >> 4) * 8;
    const int ar = wr * 64 + fr;
    const int br = wc * 64 + fr;

    load_tiles(0);
    for (int kk = 0; kk < 32; ++kk) {
        __syncthreads();
        *reinterpret_cast<bf16x8*>(&sAh[so0]) = rA0h;
        *reinterpret_cast<bf16x8*>(&sAh[so1]) = rA1h;
        *reinterpret_cast<bf16x8*>(&sAl[so0]) = rA0l;
        *reinterpret_cast<bf16x8*>(&sAl[so1]) = rA1l;
        *reinterpret_cast<bf16x8*>(&sBh[so0]) = rB0h;
        *reinterpret_cast<bf16x8*>(&sBh[so1]) = rB1h;
        __syncthreads();
        if (kk < 31) load_tiles(kk + 1);

        bf16x8 fa_h[4], fa_l[4], fb_h[4];
#pragma unroll
        for (int m = 0; m < 4; ++m) {
            fa_h[m] = *reinterpret_cast<const bf16x8*>(&sAh[(ar + m * 16) * LDP + fk]);
            fa_l[m] = *reinterpret_cast<const bf16x8*>(&sAl[(ar + m * 16) * LDP + fk]);
        }
#pragma unroll
        for (int n = 0; n < 4; ++n)
            fb_h[n] = *reinterpret_cast<const bf16x8*>(&sBh[(br + n * 16) * LDP + fk]);
#pragma unroll
        for (int m = 0; m < 4; ++m)
#pragma unroll
            for (int n = 0; n < 4; ++n) {
                acc[m][n] = __builtin_amdgcn_mfma_f32_16x16x32_bf16(fa_h[m], fb_h[n], acc[m][n], 0, 0, 0);
                acc[m][n] = __builtin_amdgcn_mfma_f32_16x16x32_bf16(fa_l[m], fb_h[n], acc[m][n], 0, 0, 0);
            }
    }

    const int er4 = (l >> 4) * 4;
    float bvv[4];
#pragma unroll
    for (int n = 0; n < 4; ++n) bvv[n] = bias[n0 + wc * 64 + n * 16 + fr];

    if (z >= 2) {
        float* C = (z == 2) ? Vp : outp;
#pragma unroll
        for (int m = 0; m < 4; ++m)
#pragma unroll
            for (int n = 0; n < 4; ++n) {
                const int col = n0 + wc * 64 + n * 16 + fr;
                const size_t rb = (size_t)(m0 + wr * 64 + m * 16 + er4) * 1024 + col;
#pragma unroll
                for (int r = 0; r < 4; ++r) C[rb + (size_t)r * 1024] = acc[m][n][r] + bvv[n];
            }
    } else {
        // bias + phase rotation + scale + bf16 store.
        // Q: sc = (1/8)*log2(e) so attn can use exp2 directly; K: sc = 1.
        u16* Dh = z ? Krh : Qrh;
        u16* Dl = Qrl;  // only used when z==0
        const float sc = z ? 1.0f : 0.18033688011112042f;
        const int head = bx * 2 + wc;
        float sv, cv;
        sincosf(phase[head], &sv, &cv);
#pragma unroll
        for (int m = 0; m < 4; ++m)
#pragma unroll
            for (int n = 0; n < 2; ++n) {
#pragma unroll
                for (int r = 0; r < 4; ++r) {
                    const float xr = acc[m][n][r] + bvv[n];
                    const float xi = acc[m][n + 2][r] + bvv[n + 2];
                    const float o0 = (xr * cv - xi * sv) * sc;
                    const float o1 = (xr * sv + xi * cv) * sc;
                    const int row = m0 + wr * 64 + m * 16 + er4 + r;
                    const size_t i0 = (size_t)row * 1024 + head * 64 + n * 16 + fr;
                    u16 hh, ll;
                    split2(o0, hh, ll);
                    Dh[i0] = hh;
                    if (z == 0) Dl[i0] = ll;
                    split2(o1, hh, ll);
                    Dh[i0 + 32] = hh;
                    if (z == 0) Dl[i0 + 32] = ll;
                }
            }
    }
}

// ---------------- transpose V' -> V^T[bh][d][s] (bf16 hi only) ------------
__global__ __launch_bounds__(256) void k_transv(const float* __restrict__ Vp,
                                                u16* __restrict__ VTh) {
    __shared__ __attribute__((aligned(16))) float tl[64 * 68];
    const int s0 = blockIdx.x * 64;
    const int bh = blockIdx.y;
    const int b = bh >> 4, h = bh & 15;
    const int t = threadIdx.x;
    {
        const int row = t >> 2, cb = (t & 3) * 16;
        const float* src = Vp + ((size_t)b * 2048 + s0 + row) * 1024 + h * 64 + cb;
#pragma unroll
        for (int j = 0; j < 16; j += 4)
            *reinterpret_cast<float4*>(&tl[row * 68 + cb + j]) =
                *reinterpret_cast<const float4*>(&src[j]);
    }
    __syncthreads();
    const int d = t >> 2, sb = (t & 3) * 16;
    u16x8 vh0, vh1;
#pragma unroll
    for (int j = 0; j < 8; ++j) {
        vh0[j] = f2bf(tl[(sb + j) * 68 + d]);
        vh1[j] = f2bf(tl[(sb + 8 + j) * 68 + d]);
    }
    const size_t ob = ((size_t)bh * 64 + d) * 2048 + s0 + sb;
    *reinterpret_cast<u16x8*>(&VTh[ob]) = vh0;
    *reinterpret_cast<u16x8*>(&VTh[ob + 8]) = vh1;
}

// ---------------- flash attention (fixed-max softmax, exp2 path) ----------
// grid flat = 1024; XCD swizzle. Wave w owns q rows w*16..+15.
// S' = S*log2e via pre-scaled Q; acc init = -12*log2e; P = exp2(s).
// K/V LDS: [64][64] u16, XOR swizzle idx ^= (row&7)<<3 (conflict-free b128).
#define LDRP 68  // P LDS row (136 B)
#define SM_M2 17.312340490667562f  // 12 * log2(e)
__global__ __launch_bounds__(256) void k_attn(
    const u16* __restrict__ Qh, const u16* __restrict__ Ql,
    const u16* __restrict__ Kh,
    const u16* __restrict__ VTh,
    u16* __restrict__ AOh, u16* __restrict__ AOl) {
    // unified LDS: K [0,4096), V [4096,8192), P [8192,12544) u16
    __shared__ __attribute__((aligned(16))) u16 smem[4096 + 4096 + 64 * LDRP];
    u16* sKh = smem;
    u16* sVh = smem + 4096;
    u16* sPh = smem + 8192;

    const int t = threadIdx.x;
    const int l = t & 63, w = t >> 6;
    const int flat = blockIdx.y * 32 + blockIdx.x;          // 0..1023
    const int tau = (flat & 7) * 128 + (flat >> 3);
    const int q0 = (tau & 31) * 64;
    const int bh = tau >> 5;
    const int b = bh >> 4, h = bh & 15;
    const size_t qrow0 = (size_t)b * 2048 + q0;

    const u16* Qb_h = Qh + qrow0 * 1024 + h * 64;
    const u16* Qb_l = Ql + qrow0 * 1024 + h * 64;
    const u16* Kb_h = Kh + (size_t)b * 2048 * 1024 + h * 64;
    const u16* Vb_h = VTh + (size_t)bh * 64 * 2048;

    const int fr = l & 15;
    const int fk = (l >> 4) * 8;

    bf16x8 aqh[2], aql[2];
#pragma unroll
    for (int ks = 0; ks < 2; ++ks) {
        const size_t qo = (size_t)(w * 16 + fr) * 1024 + ks * 32 + fk;
        aqh[ks] = g8(Qb_h + qo);
        aql[ks] = g8(Qb_l + qo);
    }

    bf16x8 vone;
#pragma unroll
    for (int j = 0; j < 8; ++j) vone[j] = (short)0x3F80;

    f32x4 aco[4];
    f32x4 acl = (f32x4){0.f, 0.f, 0.f, 0.f};
#pragma unroll
    for (int m = 0; m < 4; ++m) aco[m] = (f32x4){0.f, 0.f, 0.f, 0.f};

    const int sr = t >> 3, sc = (t & 7) * 8;  // staging: row sr(+32), col sc
    bf16x8 rKh[2], rVh[2];
    auto load_kv = [&](int tt) {
        const int kv0 = tt * 64;
#pragma unroll
        for (int i = 0; i < 2; ++i) {
            const int r2 = sr + i * 32;
            rKh[i] = g8(Kb_h + (size_t)(kv0 + r2) * 1024 + sc);
            rVh[i] = g8(Vb_h + (size_t)r2 * 2048 + kv0 + sc);
        }
    };
    // swizzled LDS staging offsets (16B-aligned, XOR row&7 into slot bits)
    int soff[2];
#pragma unroll
    for (int i = 0; i < 2; ++i) {
        const int r2 = sr + i * 32;
        soff[i] = r2 * 64 + (sc ^ ((r2 & 7) << 3));
    }
    // swizzled read offsets: row n*16+fr (K) / m*16+fr (V), col ks*32+fk
    const int rswz = (fr & 7) << 3;

    load_kv(0);
    for (int tt = 0; tt < 32; ++tt) {
        __syncthreads();
#pragma unroll
        for (int i = 0; i < 2; ++i) {
            *reinterpret_cast<bf16x8*>(&sKh[soff[i]]) = rKh[i];
            *reinterpret_cast<bf16x8*>(&sVh[soff[i]]) = rVh[i];
        }
        __syncthreads();
        if (tt < 31) load_kv(tt + 1);

        // ---- QK^T: (Qh + Ql) * Kh, acc pre-biased with -12*log2e ----
        f32x4 s[4];
#pragma unroll
        for (int n = 0; n < 4; ++n) {
            s[n] = (f32x4){-SM_M2, -SM_M2, -SM_M2, -SM_M2};
#pragma unroll
            for (int ks = 0; ks < 2; ++ks) {
                bf16x8 bkh = *reinterpret_cast<const bf16x8*>(
                    &sKh[(n * 16 + fr) * 64 + ((ks * 32 + fk) ^ rswz)]);
                s[n] = __builtin_amdgcn_mfma_f32_16x16x32_bf16(aqh[ks], bkh, s[n], 0, 0, 0);
                s[n] = __builtin_amdgcn_mfma_f32_16x16x32_bf16(aql[ks], bkh, s[n], 0, 0, 0);
            }
        }

        // ---- P = exp2(s), straight to LDS ----
#pragma unroll
        for (int n = 0; n < 4; ++n)
#pragma unroll
            for (int r = 0; r < 4; ++r) {
                const float p = fast_exp2(s[n][r]);
                const int off = (w * 16 + (l >> 4) * 4 + r) * LDRP + n * 16 + (l & 15);
                sPh[off] = f2bf(p);
            }

        // ---- PV: O^T += Vh * P^T ; l += ones * P^T ----
        bf16x8 bph[2];
#pragma unroll
        for (int ks = 0; ks < 2; ++ks)
            bph[ks] = *reinterpret_cast<const bf16x8*>(&sPh[(w * 16 + fr) * LDRP + ks * 32 + fk]);
#pragma unroll
        for (int m = 0; m < 4; ++m)
#pragma unroll
            for (int ks = 0; ks < 2; ++ks) {
                bf16x8 avh = *reinterpret_cast<const bf16x8*>(
                    &sVh[(m * 16 + fr) * 64 + ((ks * 32 + fk) ^ rswz)]);
                aco[m] = __builtin_amdgcn_mfma_f32_16x16x32_bf16(avh, bph[ks], aco[m], 0, 0, 0);
            }
#pragma unroll
        for (int ks = 0; ks < 2; ++ks)
            acl = __builtin_amdgcn_mfma_f32_16x16x32_bf16(vone, bph[ks], acl, 0, 0, 0);
    }

    const float inv = 1.0f / acl[0];
#pragma unroll
    for (int m = 0; m < 4; ++m) aco[m] *= inv;

    // two-pass transpose O^T[d][q] -> O[q][d] via [32][68] fp32 (8704 B over
    // dead K/V region), then coalesced split store.
    float* Ol = reinterpret_cast<float*>(smem);
    const int myq = w * 16 + (l & 15);
#pragma unroll
    for (int p = 0; p < 2; ++p) {
        __syncthreads();
        if ((w >> 1) == p) {
            const int qr = myq - p * 32;
#pragma unroll
            for (int m = 0; m < 4; ++m)
#pragma unroll
                for (int r = 0; r < 4; ++r)
                    Ol[qr * 68 + m * 16 + (l >> 4) * 4 + r] = aco[m][r];
        }
        __syncthreads();
        {
            const int qr = t >> 3, cb = (t & 7) * 8;
            const float* srcp = &Ol[qr * 68 + cb];
            u16x8 oh, olo;
#pragma unroll
            for (int j = 0; j < 8; ++j) {
                u16 hi, lo;
                split2(srcp[j], hi, lo);
                oh[j] = hi; olo[j] = lo;
            }
            const size_t ob = (qrow0 + p * 32 + qr) * 1024 + h * 64 + cb;
            *reinterpret_cast<u16x8*>(&AOh[ob]) = oh;
            *reinterpret_cast<u16x8*>(&AOl[ob]) = olo;
        }
    }
}

// ---------------- host ----------------
extern "C" void kernel_launch(void* const* d_in, const int* in_sizes, int n_in,
                              void* d_out, int out_size, void* d_ws, size_t ws_size,
                              hipStream_t stream) {
    const float* q = (const float*)d_in[0];
    const float* k = (const float*)d_in[1];
    const float* v = (const float*)d_in[2];
    const float* Wq = (const float*)d_in[3];
    const float* bq = (const float*)d_in[4];
    const float* Wk = (const float*)d_in[5];
    const float* bk = (const float*)d_in[6];
    const float* Wv = (const float*)d_in[7];
    const float* bv = (const float*)d_in[8];
    const float* Wo = (const float*)d_in[9];
    const float* bo = (const float*)d_in[10];
    const float* phase = (const float*)d_in[11];
    float* out = (float*)d_out;

    char* ws = (char*)d_ws;
    const size_t MB = 1u << 20;
    u16* Wq_h = (u16*)(ws + 0 * MB);
    u16* Wk_h = (u16*)(ws + 2 * MB);
    u16* Wv_h = (u16*)(ws + 4 * MB);
    u16* Wo_h = (u16*)(ws + 6 * MB);
    u16* q_h = (u16*)(ws + 16 * MB);
    u16* q_l = (u16*)(ws + 24 * MB);
    u16* k_h = (u16*)(ws + 32 * MB);
    u16* k_l = (u16*)(ws + 40 * MB);
    u16* v_h = (u16*)(ws + 48 * MB);
    u16* v_l = (u16*)(ws + 56 * MB);
    u16* QR_h = (u16*)(ws + 64 * MB);
    u16* QR_l = (u16*)(ws + 72 * MB);
    u16* KR_h = (u16*)(ws + 80 * MB);
    float* Vp = (float*)(ws + 96 * MB);
    u16* VT_h = (u16*)(ws + 48 * MB);
    u16* AO_h = (u16*)(ws + 16 * MB);
    u16* AO_l = (u16*)(ws + 24 * MB);

    k_splitX<<<dim3(4096, 3), 256, 0, stream>>>(q, k, v, q_h, q_l, k_h, k_l, v_h, v_l);
    k_splitW<<<dim3(1024, 4), 256, 0, stream>>>(Wq, Wk, Wv, Wo, Wq_h, Wk_h, Wv_h, Wo_h);
    k_gemm<<<dim3(8, 32, 3), 256, 0, stream>>>(
        q_h, q_l, k_h, k_l, v_h, v_l, AO_h, AO_l,
        Wq_h, Wk_h, Wv_h, Wo_h,
        bq, bk, bv, bo, phase, QR_h, QR_l, KR_h, Vp, out, 0);
    k_transv<<<dim3(32, 32), 256, 0, stream>>>(Vp, VT_h);
    k_attn<<<dim3(32, 32), 256, 0, stream>>>(QR_h, QR_l, KR_h, VT_h, AO_h, AO_l);
    k_gemm<<<dim3(8, 32, 1), 256, 0, stream>>>(
        q_h, q_l, k_h, k_l, v_h, v_l, AO_h, AO_l,
        Wq_h, Wk_h, Wv_h, Wo_h,
        bq, bk, bv, bo, phase, QR_h, QR_l, KR_h, Vp, out, 3);
    (void)in_sizes; (void)n_in; (void)out_size; (void)ws_size;
}

// Round 10
// 196.140 us; speedup vs baseline: 1.1203x; 1.1203x over previous
//
#include <hip/hip_runtime.h>
#include <hip/hip_bf16.h>

// PhaseSynchronizedAttention: B=2 S=2048 D=1024 H=16 DK=64, fp32 in/out.
// Round 10: R9's swizzle+exp2 kept, but K/V/P back to SEPARATE __shared__
// arrays (R9's unified smem block defeated LDS alias analysis -> lgkmcnt
// serialization between P-writes and V-reads; +46k cy/CU stall).

typedef short bf16x8 __attribute__((ext_vector_type(8)));
typedef float f32x4 __attribute__((ext_vector_type(4)));
typedef unsigned short u16;
typedef unsigned short u16x8 __attribute__((ext_vector_type(8)));
typedef unsigned short u16x4 __attribute__((ext_vector_type(4)));

static __device__ __forceinline__ u16 f2bf(float x) {
    __hip_bfloat16 b = __float2bfloat16(x);
    return *reinterpret_cast<u16*>(&b);
}
static __device__ __forceinline__ float bf2f(u16 u) {
    __hip_bfloat16 b = *reinterpret_cast<__hip_bfloat16*>(&u);
    return __bfloat162float(b);
}
static __device__ __forceinline__ void split2(float x, u16& hi, u16& lo) {
    hi = f2bf(x);
    lo = f2bf(x - bf2f(hi));
}
static __device__ __forceinline__ bf16x8 g8(const u16* p) {
    return *reinterpret_cast<const bf16x8*>(p);
}
static __device__ __forceinline__ float fast_exp2(float x) {
#if __has_builtin(__builtin_amdgcn_exp2f)
    return __builtin_amdgcn_exp2f(x);
#else
    return exp2f(x);
#endif
}

// ---------------- split fp32 -> bf16 hi/lo (fused: q,k,v) ----------------
__global__ void k_splitX(const float* __restrict__ q, const float* __restrict__ k,
                         const float* __restrict__ v,
                         u16* __restrict__ qh, u16* __restrict__ ql,
                         u16* __restrict__ kh, u16* __restrict__ kl,
                         u16* __restrict__ vh, u16* __restrict__ vl) {
    const int i = blockIdx.x * 256 + threadIdx.x;  // grid.x = 4096, n4 = 1048576
    const float* s;
    u16 *H, *L;
    if (blockIdx.y == 0) { s = q; H = qh; L = ql; }
    else if (blockIdx.y == 1) { s = k; H = kh; L = kl; }
    else { s = v; H = vh; L = vl; }
    float4 val = reinterpret_cast<const float4*>(s)[i];
    u16x4 h, l;
    u16 th, tl2;
    split2(val.x, th, tl2); h[0] = th; l[0] = tl2;
    split2(val.y, th, tl2); h[1] = th; l[1] = tl2;
    split2(val.z, th, tl2); h[2] = th; l[2] = tl2;
    split2(val.w, th, tl2); h[3] = th; l[3] = tl2;
    reinterpret_cast<u16x4*>(H)[i] = h;
    reinterpret_cast<u16x4*>(L)[i] = l;
}

// ---------------- split hi-only (fused: Wq,Wk,Wv,Wo) ----------------
__global__ void k_splitW(const float* __restrict__ w0, const float* __restrict__ w1,
                         const float* __restrict__ w2, const float* __restrict__ w3,
                         u16* __restrict__ h0, u16* __restrict__ h1,
                         u16* __restrict__ h2, u16* __restrict__ h3) {
    const int i = blockIdx.x * 256 + threadIdx.x;  // grid.x = 1024, n4 = 262144
    const float* s;
    u16* H;
    if (blockIdx.y == 0) { s = w0; H = h0; }
    else if (blockIdx.y == 1) { s = w1; H = h1; }
    else if (blockIdx.y == 2) { s = w2; H = h2; }
    else { s = w3; H = h3; }
    float4 val = reinterpret_cast<const float4*>(s)[i];
    u16x4 h;
    h[0] = f2bf(val.x);
    h[1] = f2bf(val.y);
    h[2] = f2bf(val.z);
    h[3] = f2bf(val.w);
    reinterpret_cast<u16x4*>(H)[i] = h;
}

// ---------------- unified GEMM: C[M,1024] = (Ah+Al) @ Bh^T + bias ---------
// z: 0=Q-proj(rotate, scale incl. log2e, split out), 1=K-proj(rotate,hi out),
// 2=V-proj(fp32 out), 3=out-proj(fp32 out). XCD swizzle.
#define LDP 40  // padded LDS row in elems (80 B)
__global__ __launch_bounds__(256) void k_gemm(
    const u16* __restrict__ qh, const u16* __restrict__ ql,
    const u16* __restrict__ kh, const u16* __restrict__ kl,
    const u16* __restrict__ vh, const u16* __restrict__ vl,
    const u16* __restrict__ aoh, const u16* __restrict__ aol,
    const u16* __restrict__ Wqh, const u16* __restrict__ Wkh,
    const u16* __restrict__ Wvh, const u16* __restrict__ Woh,
    const float* __restrict__ bq, const float* __restrict__ bk,
    const float* __restrict__ bv_, const float* __restrict__ bo,
    const float* __restrict__ phase,
    u16* __restrict__ Qrh, u16* __restrict__ Qrl,
    u16* __restrict__ Krh,
    float* __restrict__ Vp, float* __restrict__ outp, int zoff) {
    __shared__ __attribute__((aligned(16))) u16 sAh[128 * LDP];
    __shared__ __attribute__((aligned(16))) u16 sAl[128 * LDP];
    __shared__ __attribute__((aligned(16))) u16 sBh[128 * LDP];

    const int z = blockIdx.z + zoff;
    const u16 *Ah, *Al, *Bh;
    const float* bias;
    if (z == 0) { Ah = qh; Al = ql; Bh = Wqh; bias = bq; }
    else if (z == 1) { Ah = kh; Al = kl; Bh = Wkh; bias = bk; }
    else if (z == 2) { Ah = vh; Al = vl; Bh = Wvh; bias = bv_; }
    else { Ah = aoh; Al = aol; Bh = Woh; bias = bo; }

    // XCD-aware tile remap (HW: xcd = flat_wg % 8)
    const int flat = blockIdx.y * 8 + blockIdx.x;           // 0..255
    const int tau = (flat & 7) * 32 + (flat >> 3);          // bijective
    const int bx = tau & 7, by = tau >> 3;

    const int t = threadIdx.x;
    const int l = t & 63, w = t >> 6;
    const int wr = w >> 1, wc = w & 1;
    const int m0 = by * 128, n0 = bx * 128;

    const int srow = t >> 2;
    const int scol = (t & 3) * 8;
    const u16* pA0h = Ah + (size_t)(m0 + srow) * 1024 + scol;
    const u16* pA1h = Ah + (size_t)(m0 + 64 + srow) * 1024 + scol;
    const u16* pA0l = Al + (size_t)(m0 + srow) * 1024 + scol;
    const u16* pA1l = Al + (size_t)(m0 + 64 + srow) * 1024 + scol;
    const u16* pB0h = Bh + (size_t)(n0 + srow) * 1024 + scol;
    const u16* pB1h = Bh + (size_t)(n0 + 64 + srow) * 1024 + scol;
    const int so0 = srow * LDP + scol;
    const int so1 = (srow + 64) * LDP + scol;

    bf16x8 rA0h, rA1h, rA0l, rA1l, rB0h, rB1h;
    auto load_tiles = [&](int kk) {
        const int ko = kk * 32;
        rA0h = g8(pA0h + ko); rA1h = g8(pA1h + ko);
        rA0l = g8(pA0l + ko); rA1l = g8(pA1l + ko);
        rB0h = g8(pB0h + ko); rB1h = g8(pB1h + ko);
    };

    f32x4 acc[4][4];
#pragma unroll
    for (int m = 0; m < 4; ++m)
#pragma unroll
        for (int n = 0; n < 4; ++n) acc[m][n] = (f32x4){0.f, 0.f, 0.f, 0.f};

    const int fr = l & 15;
    const int fk = (l >> 4) * 8;
    const int ar = wr * 64 + fr;
    const int br = wc * 64 + fr;

    load_tiles(0);
    for (int kk = 0; kk < 32; ++kk) {
        __syncthreads();
        *reinterpret_cast<bf16x8*>(&sAh[so0]) = rA0h;
        *reinterpret_cast<bf16x8*>(&sAh[so1]) = rA1h;
        *reinterpret_cast<bf16x8*>(&sAl[so0]) = rA0l;
        *reinterpret_cast<bf16x8*>(&sAl[so1]) = rA1l;
        *reinterpret_cast<bf16x8*>(&sBh[so0]) = rB0h;
        *reinterpret_cast<bf16x8*>(&sBh[so1]) = rB1h;
        __syncthreads();
        if (kk < 31) load_tiles(kk + 1);

        bf16x8 fa_h[4], fa_l[4], fb_h[4];
#pragma unroll
        for (int m = 0; m < 4; ++m) {
            fa_h[m] = *reinterpret_cast<const bf16x8*>(&sAh[(ar + m * 16) * LDP + fk]);
            fa_l[m] = *reinterpret_cast<const bf16x8*>(&sAl[(ar + m * 16) * LDP + fk]);
        }
#pragma unroll
        for (int n = 0; n < 4; ++n)
            fb_h[n] = *reinterpret_cast<const bf16x8*>(&sBh[(br + n * 16) * LDP + fk]);
#pragma unroll
        for (int m = 0; m < 4; ++m)
#pragma unroll
            for (int n = 0; n < 4; ++n) {
                acc[m][n] = __builtin_amdgcn_mfma_f32_16x16x32_bf16(fa_h[m], fb_h[n], acc[m][n], 0, 0, 0);
                acc[m][n] = __builtin_amdgcn_mfma_f32_16x16x32_bf16(fa_l[m], fb_h[n], acc[m][n], 0, 0, 0);
            }
    }

    const int er4 = (l >> 4) * 4;
    float bvv[4];
#pragma unroll
    for (int n = 0; n < 4; ++n) bvv[n] = bias[n0 + wc * 64 + n * 16 + fr];

    if (z >= 2) {
        float* C = (z == 2) ? Vp : outp;
#pragma unroll
        for (int m = 0; m < 4; ++m)
#pragma unroll
            for (int n = 0; n < 4; ++n) {
                const int col = n0 + wc * 64 + n * 16 + fr;
                const size_t rb = (size_t)(m0 + wr * 64 + m * 16 + er4) * 1024 + col;
#pragma unroll
                for (int r = 0; r < 4; ++r) C[rb + (size_t)r * 1024] = acc[m][n][r] + bvv[n];
            }
    } else {
        // bias + phase rotation + scale + bf16 store.
        // Q: sc = (1/8)*log2(e) so attn can use exp2 directly; K: sc = 1.
        u16* Dh = z ? Krh : Qrh;
        u16* Dl = Qrl;  // only used when z==0
        const float sc = z ? 1.0f : 0.18033688011112042f;
        const int head = bx * 2 + wc;
        float sv, cv;
        sincosf(phase[head], &sv, &cv);
#pragma unroll
        for (int m = 0; m < 4; ++m)
#pragma unroll
            for (int n = 0; n < 2; ++n) {
#pragma unroll
                for (int r = 0; r < 4; ++r) {
                    const float xr = acc[m][n][r] + bvv[n];
                    const float xi = acc[m][n + 2][r] + bvv[n + 2];
                    const float o0 = (xr * cv - xi * sv) * sc;
                    const float o1 = (xr * sv + xi * cv) * sc;
                    const int row = m0 + wr * 64 + m * 16 + er4 + r;
                    const size_t i0 = (size_t)row * 1024 + head * 64 + n * 16 + fr;
                    u16 hh, ll;
                    split2(o0, hh, ll);
                    Dh[i0] = hh;
                    if (z == 0) Dl[i0] = ll;
                    split2(o1, hh, ll);
                    Dh[i0 + 32] = hh;
                    if (z == 0) Dl[i0 + 32] = ll;
                }
            }
    }
}

// ---------------- transpose V' -> V^T[bh][d][s] (bf16 hi only) ------------
__global__ __launch_bounds__(256) void k_transv(const float* __restrict__ Vp,
                                                u16* __restrict__ VTh) {
    __shared__ __attribute__((aligned(16))) float tl[64 * 68];
    const int s0 = blockIdx.x * 64;
    const int bh = blockIdx.y;
    const int b = bh >> 4, h = bh & 15;
    const int t = threadIdx.x;
    {
        const int row = t >> 2, cb = (t & 3) * 16;
        const float* src = Vp + ((size_t)b * 2048 + s0 + row) * 1024 + h * 64 + cb;
#pragma unroll
        for (int j = 0; j < 16; j += 4)
            *reinterpret_cast<float4*>(&tl[row * 68 + cb + j]) =
                *reinterpret_cast<const float4*>(&src[j]);
    }
    __syncthreads();
    const int d = t >> 2, sb = (t & 3) * 16;
    u16x8 vh0, vh1;
#pragma unroll
    for (int j = 0; j < 8; ++j) {
        vh0[j] = f2bf(tl[(sb + j) * 68 + d]);
        vh1[j] = f2bf(tl[(sb + 8 + j) * 68 + d]);
    }
    const size_t ob = ((size_t)bh * 64 + d) * 2048 + s0 + sb;
    *reinterpret_cast<u16x8*>(&VTh[ob]) = vh0;
    *reinterpret_cast<u16x8*>(&VTh[ob + 8]) = vh1;
}

// ---------------- flash attention (fixed-max softmax, exp2 path) ----------
// grid flat = 1024; XCD swizzle. Wave w owns q rows w*16..+15.
// S' = S*log2e via pre-scaled Q; acc init = -12*log2e; P = exp2(s).
// K/V LDS: separate [64*64] u16 arrays, XOR swizzle idx ^= (row&7)<<3.
#define LDRP 68  // P LDS row (136 B)
#define SM_M2 17.312340490667562f  // 12 * log2(e)
__global__ __launch_bounds__(256) void k_attn(
    const u16* __restrict__ Qh, const u16* __restrict__ Ql,
    const u16* __restrict__ Kh,
    const u16* __restrict__ VTh,
    u16* __restrict__ AOh, u16* __restrict__ AOl) {
    __shared__ __attribute__((aligned(16))) u16 sKh[64 * 64];
    __shared__ __attribute__((aligned(16))) u16 sVh[64 * 64];
    __shared__ __attribute__((aligned(16))) u16 sPh[64 * LDRP];

    const int t = threadIdx.x;
    const int l = t & 63, w = t >> 6;
    const int flat = blockIdx.y * 32 + blockIdx.x;          // 0..1023
    const int tau = (flat & 7) * 128 + (flat >> 3);
    const int q0 = (tau & 31) * 64;
    const int bh = tau >> 5;
    const int b = bh >> 4, h = bh & 15;
    const size_t qrow0 = (size_t)b * 2048 + q0;

    const u16* Qb_h = Qh + qrow0 * 1024 + h * 64;
    const u16* Qb_l = Ql + qrow0 * 1024 + h * 64;
    const u16* Kb_h = Kh + (size_t)b * 2048 * 1024 + h * 64;
    const u16* Vb_h = VTh + (size_t)bh * 64 * 2048;

    const int fr = l & 15;
    const int fk = (l >> 4) * 8;

    bf16x8 aqh[2], aql[2];
#pragma unroll
    for (int ks = 0; ks < 2; ++ks) {
        const size_t qo = (size_t)(w * 16 + fr) * 1024 + ks * 32 + fk;
        aqh[ks] = g8(Qb_h + qo);
        aql[ks] = g8(Qb_l + qo);
    }

    bf16x8 vone;
#pragma unroll
    for (int j = 0; j < 8; ++j) vone[j] = (short)0x3F80;

    f32x4 aco[4];
    f32x4 acl = (f32x4){0.f, 0.f, 0.f, 0.f};
#pragma unroll
    for (int m = 0; m < 4; ++m) aco[m] = (f32x4){0.f, 0.f, 0.f, 0.f};

    const int sr = t >> 3, sc = (t & 7) * 8;  // staging: row sr(+32), col sc
    bf16x8 rKh[2], rVh[2];
    auto load_kv = [&](int tt) {
        const int kv0 = tt * 64;
#pragma unroll
        for (int i = 0; i < 2; ++i) {
            const int r2 = sr + i * 32;
            rKh[i] = g8(Kb_h + (size_t)(kv0 + r2) * 1024 + sc);
            rVh[i] = g8(Vb_h + (size_t)r2 * 2048 + kv0 + sc);
        }
    };
    // swizzled LDS staging offsets (16B-aligned, XOR row&7 into slot bits)
    int soff[2];
#pragma unroll
    for (int i = 0; i < 2; ++i) {
        const int r2 = sr + i * 32;
        soff[i] = r2 * 64 + (sc ^ ((r2 & 7) << 3));
    }
    // swizzled read offsets: row has fr in low bits; col ks*32+fk
    const int rswz = (fr & 7) << 3;

    load_kv(0);
    for (int tt = 0; tt < 32; ++tt) {
        __syncthreads();
#pragma unroll
        for (int i = 0; i < 2; ++i) {
            *reinterpret_cast<bf16x8*>(&sKh[soff[i]]) = rKh[i];
            *reinterpret_cast<bf16x8*>(&sVh[soff[i]]) = rVh[i];
        }
        __syncthreads();
        if (tt < 31) load_kv(tt + 1);

        // ---- QK^T: (Qh + Ql) * Kh, acc pre-biased with -12*log2e ----
        f32x4 s[4];
#pragma unroll
        for (int n = 0; n < 4; ++n) {
            s[n] = (f32x4){-SM_M2, -SM_M2, -SM_M2, -SM_M2};
#pragma unroll
            for (int ks = 0; ks < 2; ++ks) {
                bf16x8 bkh = *reinterpret_cast<const bf16x8*>(
                    &sKh[(n * 16 + fr) * 64 + ((ks * 32 + fk) ^ rswz)]);
                s[n] = __builtin_amdgcn_mfma_f32_16x16x32_bf16(aqh[ks], bkh, s[n], 0, 0, 0);
                s[n] = __builtin_amdgcn_mfma_f32_16x16x32_bf16(aql[ks], bkh, s[n], 0, 0, 0);
            }
        }

        // ---- P = exp2(s), straight to LDS ----
#pragma unroll
        for (int n = 0; n < 4; ++n)
#pragma unroll
            for (int r = 0; r < 4; ++r) {
                const float p = fast_exp2(s[n][r]);
                const int off = (w * 16 + (l >> 4) * 4 + r) * LDRP + n * 16 + (l & 15);
                sPh[off] = f2bf(p);
            }

        // ---- PV: O^T += Vh * P^T ; l += ones * P^T ----
        bf16x8 bph[2];
#pragma unroll
        for (int ks = 0; ks < 2; ++ks)
            bph[ks] = *reinterpret_cast<const bf16x8*>(&sPh[(w * 16 + fr) * LDRP + ks * 32 + fk]);
#pragma unroll
        for (int m = 0; m < 4; ++m)
#pragma unroll
            for (int ks = 0; ks < 2; ++ks) {
                bf16x8 avh = *reinterpret_cast<const bf16x8*>(
                    &sVh[(m * 16 + fr) * 64 + ((ks * 32 + fk) ^ rswz)]);
                aco[m] = __builtin_amdgcn_mfma_f32_16x16x32_bf16(avh, bph[ks], aco[m], 0, 0, 0);
            }
#pragma unroll
        for (int ks = 0; ks < 2; ++ks)
            acl = __builtin_amdgcn_mfma_f32_16x16x32_bf16(vone, bph[ks], acl, 0, 0, 0);
    }

    const float inv = 1.0f / acl[0];
#pragma unroll
    for (int m = 0; m < 4; ++m) aco[m] *= inv;

    // two-pass transpose O^T[d][q] -> O[q][d] via [32][68] fp32 region over
    // sPh (8704 B, exact fit; dead after last PV read, barrier-protected).
    float* Ol = reinterpret_cast<float*>(sPh);
    const int myq = w * 16 + (l & 15);
#pragma unroll
    for (int p = 0; p < 2; ++p) {
        __syncthreads();
        if ((w >> 1) == p) {
            const int qr = myq - p * 32;
#pragma unroll
            for (int m = 0; m < 4; ++m)
#pragma unroll
                for (int r = 0; r < 4; ++r)
                    Ol[qr * 68 + m * 16 + (l >> 4) * 4 + r] = aco[m][r];
        }
        __syncthreads();
        {
            const int qr = t >> 3, cb = (t & 7) * 8;
            const float* srcp = &Ol[qr * 68 + cb];
            u16x8 oh, olo;
#pragma unroll
            for (int j = 0; j < 8; ++j) {
                u16 hi, lo;
                split2(srcp[j], hi, lo);
                oh[j] = hi; olo[j] = lo;
            }
            const size_t ob = (qrow0 + p * 32 + qr) * 1024 + h * 64 + cb;
            *reinterpret_cast<u16x8*>(&AOh[ob]) = oh;
            *reinterpret_cast<u16x8*>(&AOl[ob]) = olo;
        }
    }
}

// ---------------- host ----------------
extern "C" void kernel_launch(void* const* d_in, const int* in_sizes, int n_in,
                              void* d_out, int out_size, void* d_ws, size_t ws_size,
                              hipStream_t stream) {
    const float* q = (const float*)d_in[0];
    const float* k = (const float*)d_in[1];
    const float* v = (const float*)d_in[2];
    const float* Wq = (const float*)d_in[3];
    const float* bq = (const float*)d_in[4];
    const float* Wk = (const float*)d_in[5];
    const float* bk = (const float*)d_in[6];
    const float* Wv = (const float*)d_in[7];
    const float* bv = (const float*)d_in[8];
    const float* Wo = (const float*)d_in[9];
    const float* bo = (const float*)d_in[10];
    const float* phase = (const float*)d_in[11];
    float* out = (float*)d_out;

    char* ws = (char*)d_ws;
    const size_t MB = 1u << 20;
    u16* Wq_h = (u16*)(ws + 0 * MB);
    u16* Wk_h = (u16*)(ws + 2 * MB);
    u16* Wv_h = (u16*)(ws + 4 * MB);
    u16* Wo_h = (u16*)(ws + 6 * MB);
    u16* q_h = (u16*)(ws + 16 * MB);
    u16* q_l = (u16*)(ws + 24 * MB);
    u16* k_h = (u16*)(ws + 32 * MB);
    u16* k_l = (u16*)(ws + 40 * MB);
    u16* v_h = (u16*)(ws + 48 * MB);
    u16* v_l = (u16*)(ws + 56 * MB);
    u16* QR_h = (u16*)(ws + 64 * MB);
    u16* QR_l = (u16*)(ws + 72 * MB);
    u16* KR_h = (u16*)(ws + 80 * MB);
    float* Vp = (float*)(ws + 96 * MB);
    u16* VT_h = (u16*)(ws + 48 * MB);
    u16* AO_h = (u16*)(ws + 16 * MB);
    u16* AO_l = (u16*)(ws + 24 * MB);

    k_splitX<<<dim3(4096, 3), 256, 0, stream>>>(q, k, v, q_h, q_l, k_h, k_l, v_h, v_l);
    k_splitW<<<dim3(1024, 4), 256, 0, stream>>>(Wq, Wk, Wv, Wo, Wq_h, Wk_h, Wv_h, Wo_h);
    k_gemm<<<dim3(8, 32, 3), 256, 0, stream>>>(
        q_h, q_l, k_h, k_l, v_h, v_l, AO_h, AO_l,
        Wq_h, Wk_h, Wv_h, Wo_h,
        bq, bk, bv, bo, phase, QR_h, QR_l, KR_h, Vp, out, 0);
    k_transv<<<dim3(32, 32), 256, 0, stream>>>(Vp, VT_h);
    k_attn<<<dim3(32, 32), 256, 0, stream>>>(QR_h, QR_l, KR_h, VT_h, AO_h, AO_l);
    k_gemm<<<dim3(8, 32, 1), 256, 0, stream>>>(
        q_h, q_l, k_h, k_l, v_h, v_l, AO_h, AO_l,
        Wq_h, Wk_h, Wv_h, Wo_h,
        bq, bk, bv, bo, phase, QR_h, QR_l, KR_h, Vp, out, 3);
    (void)in_sizes; (void)n_in; (void)out_size; (void)ws_size;
}

// Round 11
// 188.078 us; speedup vs baseline: 1.1684x; 1.0429x over previous
//
#include <hip/hip_runtime.h>
#include <hip/hip_bf16.h>

// PhaseSynchronizedAttention: B=2 S=2048 D=1024 H=16 DK=64, fp32 in/out.
// Round 11: delete k_transv (V-proj epilogue writes V^T bf16 directly);
// merge the two split launches. k_attn unchanged from R10 (swizzle + exp2 +
// separate LDS arrays). VT moved to [96,104) (must not alias v splits that
// z==2 blocks read).

typedef short bf16x8 __attribute__((ext_vector_type(8)));
typedef float f32x4 __attribute__((ext_vector_type(4)));
typedef unsigned short u16;
typedef unsigned short u16x8 __attribute__((ext_vector_type(8)));
typedef unsigned short u16x4 __attribute__((ext_vector_type(4)));

static __device__ __forceinline__ u16 f2bf(float x) {
    __hip_bfloat16 b = __float2bfloat16(x);
    return *reinterpret_cast<u16*>(&b);
}
static __device__ __forceinline__ float bf2f(u16 u) {
    __hip_bfloat16 b = *reinterpret_cast<__hip_bfloat16*>(&u);
    return __bfloat162float(b);
}
static __device__ __forceinline__ void split2(float x, u16& hi, u16& lo) {
    hi = f2bf(x);
    lo = f2bf(x - bf2f(hi));
}
static __device__ __forceinline__ bf16x8 g8(const u16* p) {
    return *reinterpret_cast<const bf16x8*>(p);
}
static __device__ __forceinline__ float fast_exp2(float x) {
#if __has_builtin(__builtin_amdgcn_exp2f)
    return __builtin_amdgcn_exp2f(x);
#else
    return exp2f(x);
#endif
}

// ---------------- merged split: y=0,1,2 -> q,k,v (hi+lo); y=3 -> W's (hi) --
__global__ void k_split(const float* __restrict__ q, const float* __restrict__ k,
                        const float* __restrict__ v,
                        const float* __restrict__ w0, const float* __restrict__ w1,
                        const float* __restrict__ w2, const float* __restrict__ w3,
                        u16* __restrict__ qh, u16* __restrict__ ql,
                        u16* __restrict__ kh, u16* __restrict__ kl,
                        u16* __restrict__ vh, u16* __restrict__ vl,
                        u16* __restrict__ h0, u16* __restrict__ h1,
                        u16* __restrict__ h2, u16* __restrict__ h3) {
    const int i = blockIdx.x * 256 + threadIdx.x;  // grid.x = 4096 -> i < 1048576
    if (blockIdx.y == 3) {
        // four weight matrices, hi only; each 262144 float4s
        const int which = i >> 18;
        const int off = i & 262143;
        const float* s = (which == 0) ? w0 : (which == 1) ? w1 : (which == 2) ? w2 : w3;
        u16* H = (which == 0) ? h0 : (which == 1) ? h1 : (which == 2) ? h2 : h3;
        float4 val = reinterpret_cast<const float4*>(s)[off];
        u16x4 h;
        h[0] = f2bf(val.x);
        h[1] = f2bf(val.y);
        h[2] = f2bf(val.z);
        h[3] = f2bf(val.w);
        reinterpret_cast<u16x4*>(H)[off] = h;
        return;
    }
    const float* s;
    u16 *H, *L;
    if (blockIdx.y == 0) { s = q; H = qh; L = ql; }
    else if (blockIdx.y == 1) { s = k; H = kh; L = kl; }
    else { s = v; H = vh; L = vl; }
    float4 val = reinterpret_cast<const float4*>(s)[i];
    u16x4 h, l;
    u16 th, tl2;
    split2(val.x, th, tl2); h[0] = th; l[0] = tl2;
    split2(val.y, th, tl2); h[1] = th; l[1] = tl2;
    split2(val.z, th, tl2); h[2] = th; l[2] = tl2;
    split2(val.w, th, tl2); h[3] = th; l[3] = tl2;
    reinterpret_cast<u16x4*>(H)[i] = h;
    reinterpret_cast<u16x4*>(L)[i] = l;
}

// ---------------- unified GEMM: C[M,1024] = (Ah+Al) @ Bh^T + bias ---------
// z: 0=Q-proj(rotate, scale incl. log2e, split out), 1=K-proj(rotate,hi out),
// 2=V-proj(fused transpose -> V^T[bh][d][s] bf16), 3=out-proj(fp32 out).
// XCD swizzle: tau=(flat%8)*32+flat/8.
#define LDP 40  // padded LDS row in elems (80 B)
__global__ __launch_bounds__(256) void k_gemm(
    const u16* __restrict__ qh, const u16* __restrict__ ql,
    const u16* __restrict__ kh, const u16* __restrict__ kl,
    const u16* __restrict__ vh, const u16* __restrict__ vl,
    const u16* __restrict__ aoh, const u16* __restrict__ aol,
    const u16* __restrict__ Wqh, const u16* __restrict__ Wkh,
    const u16* __restrict__ Wvh, const u16* __restrict__ Woh,
    const float* __restrict__ bq, const float* __restrict__ bk,
    const float* __restrict__ bv_, const float* __restrict__ bo,
    const float* __restrict__ phase,
    u16* __restrict__ Qrh, u16* __restrict__ Qrl,
    u16* __restrict__ Krh,
    u16* __restrict__ VTh, float* __restrict__ outp, int zoff) {
    __shared__ __attribute__((aligned(16))) u16 sAh[128 * LDP];
    __shared__ __attribute__((aligned(16))) u16 sAl[128 * LDP];
    __shared__ __attribute__((aligned(16))) u16 sBh[128 * LDP];

    const int z = blockIdx.z + zoff;
    const u16 *Ah, *Al, *Bh;
    const float* bias;
    if (z == 0) { Ah = qh; Al = ql; Bh = Wqh; bias = bq; }
    else if (z == 1) { Ah = kh; Al = kl; Bh = Wkh; bias = bk; }
    else if (z == 2) { Ah = vh; Al = vl; Bh = Wvh; bias = bv_; }
    else { Ah = aoh; Al = aol; Bh = Woh; bias = bo; }

    // XCD-aware tile remap (HW: xcd = flat_wg % 8)
    const int flat = blockIdx.y * 8 + blockIdx.x;           // 0..255
    const int tau = (flat & 7) * 32 + (flat >> 3);          // bijective
    const int bx = tau & 7, by = tau >> 3;

    const int t = threadIdx.x;
    const int l = t & 63, w = t >> 6;
    const int wr = w >> 1, wc = w & 1;
    const int m0 = by * 128, n0 = bx * 128;

    const int srow = t >> 2;
    const int scol = (t & 3) * 8;
    const u16* pA0h = Ah + (size_t)(m0 + srow) * 1024 + scol;
    const u16* pA1h = Ah + (size_t)(m0 + 64 + srow) * 1024 + scol;
    const u16* pA0l = Al + (size_t)(m0 + srow) * 1024 + scol;
    const u16* pA1l = Al + (size_t)(m0 + 64 + srow) * 1024 + scol;
    const u16* pB0h = Bh + (size_t)(n0 + srow) * 1024 + scol;
    const u16* pB1h = Bh + (size_t)(n0 + 64 + srow) * 1024 + scol;
    const int so0 = srow * LDP + scol;
    const int so1 = (srow + 64) * LDP + scol;

    bf16x8 rA0h, rA1h, rA0l, rA1l, rB0h, rB1h;
    auto load_tiles = [&](int kk) {
        const int ko = kk * 32;
        rA0h = g8(pA0h + ko); rA1h = g8(pA1h + ko);
        rA0l = g8(pA0l + ko); rA1l = g8(pA1l + ko);
        rB0h = g8(pB0h + ko); rB1h = g8(pB1h + ko);
    };

    f32x4 acc[4][4];
#pragma unroll
    for (int m = 0; m < 4; ++m)
#pragma unroll
        for (int n = 0; n < 4; ++n) acc[m][n] = (f32x4){0.f, 0.f, 0.f, 0.f};

    const int fr = l & 15;
    const int fk = (l >> 4) * 8;
    const int ar = wr * 64 + fr;
    const int br = wc * 64 + fr;

    load_tiles(0);
    for (int kk = 0; kk < 32; ++kk) {
        __syncthreads();
        *reinterpret_cast<bf16x8*>(&sAh[so0]) = rA0h;
        *reinterpret_cast<bf16x8*>(&sAh[so1]) = rA1h;
        *reinterpret_cast<bf16x8*>(&sAl[so0]) = rA0l;
        *reinterpret_cast<bf16x8*>(&sAl[so1]) = rA1l;
        *reinterpret_cast<bf16x8*>(&sBh[so0]) = rB0h;
        *reinterpret_cast<bf16x8*>(&sBh[so1]) = rB1h;
        __syncthreads();
        if (kk < 31) load_tiles(kk + 1);

        bf16x8 fa_h[4], fa_l[4], fb_h[4];
#pragma unroll
        for (int m = 0; m < 4; ++m) {
            fa_h[m] = *reinterpret_cast<const bf16x8*>(&sAh[(ar + m * 16) * LDP + fk]);
            fa_l[m] = *reinterpret_cast<const bf16x8*>(&sAl[(ar + m * 16) * LDP + fk]);
        }
#pragma unroll
        for (int n = 0; n < 4; ++n)
            fb_h[n] = *reinterpret_cast<const bf16x8*>(&sBh[(br + n * 16) * LDP + fk]);
#pragma unroll
        for (int m = 0; m < 4; ++m)
#pragma unroll
            for (int n = 0; n < 4; ++n) {
                acc[m][n] = __builtin_amdgcn_mfma_f32_16x16x32_bf16(fa_h[m], fb_h[n], acc[m][n], 0, 0, 0);
                acc[m][n] = __builtin_amdgcn_mfma_f32_16x16x32_bf16(fa_l[m], fb_h[n], acc[m][n], 0, 0, 0);
            }
    }

    const int er4 = (l >> 4) * 4;
    float bvv[4];
#pragma unroll
    for (int n = 0; n < 4; ++n) bvv[n] = bias[n0 + wc * 64 + n * 16 + fr];

    if (z == 3) {
#pragma unroll
        for (int m = 0; m < 4; ++m)
#pragma unroll
            for (int n = 0; n < 4; ++n) {
                const int col = n0 + wc * 64 + n * 16 + fr;
                const size_t rb = (size_t)(m0 + wr * 64 + m * 16 + er4) * 1024 + col;
#pragma unroll
                for (int r = 0; r < 4; ++r) outp[rb + (size_t)r * 1024] = acc[m][n][r] + bvv[n];
            }
    } else if (z == 2) {
        // fused transpose: V^T[(b*16+h)*64+d][s], 4 consecutive s per thread
#pragma unroll
        for (int m = 0; m < 4; ++m) {
            const int row0 = m0 + wr * 64 + m * 16 + er4;  // s-base (mult of 4)
            const int bb = row0 >> 11;
            const int ss = row0 & 2047;
#pragma unroll
            for (int n = 0; n < 4; ++n) {
                const int col = n0 + wc * 64 + n * 16 + fr;
                const int hh_ = col >> 6, dd = col & 63;
                u16x4 vv;
#pragma unroll
                for (int r = 0; r < 4; ++r) vv[r] = f2bf(acc[m][n][r] + bvv[n]);
                *reinterpret_cast<u16x4*>(
                    &VTh[((size_t)(bb * 16 + hh_) * 64 + dd) * 2048 + ss]) = vv;
            }
        }
    } else {
        // bias + phase rotation + scale + bf16 store.
        // Q: sc = (1/8)*log2(e) so attn can use exp2 directly; K: sc = 1.
        u16* Dh = z ? Krh : Qrh;
        u16* Dl = Qrl;  // only used when z==0
        const float sc = z ? 1.0f : 0.18033688011112042f;
        const int head = bx * 2 + wc;
        float sv, cv;
        sincosf(phase[head], &sv, &cv);
#pragma unroll
        for (int m = 0; m < 4; ++m)
#pragma unroll
            for (int n = 0; n < 2; ++n) {
#pragma unroll
                for (int r = 0; r < 4; ++r) {
                    const float xr = acc[m][n][r] + bvv[n];
                    const float xi = acc[m][n + 2][r] + bvv[n + 2];
                    const float o0 = (xr * cv - xi * sv) * sc;
                    const float o1 = (xr * sv + xi * cv) * sc;
                    const int row = m0 + wr * 64 + m * 16 + er4 + r;
                    const size_t i0 = (size_t)row * 1024 + head * 64 + n * 16 + fr;
                    u16 hh, ll;
                    split2(o0, hh, ll);
                    Dh[i0] = hh;
                    if (z == 0) Dl[i0] = ll;
                    split2(o1, hh, ll);
                    Dh[i0 + 32] = hh;
                    if (z == 0) Dl[i0 + 32] = ll;
                }
            }
    }
}

// ---------------- flash attention (fixed-max softmax, exp2 path) ----------
// grid flat = 1024; XCD swizzle. Wave w owns q rows w*16..+15.
// S' = S*log2e via pre-scaled Q; acc init = -12*log2e; P = exp2(s).
// K/V LDS: separate [64*64] u16 arrays, XOR swizzle idx ^= (row&7)<<3.
#define LDRP 68  // P LDS row (136 B)
#define SM_M2 17.312340490667562f  // 12 * log2(e)
__global__ __launch_bounds__(256) void k_attn(
    const u16* __restrict__ Qh, const u16* __restrict__ Ql,
    const u16* __restrict__ Kh,
    const u16* __restrict__ VTh,
    u16* __restrict__ AOh, u16* __restrict__ AOl) {
    __shared__ __attribute__((aligned(16))) u16 sKh[64 * 64];
    __shared__ __attribute__((aligned(16))) u16 sVh[64 * 64];
    __shared__ __attribute__((aligned(16))) u16 sPh[64 * LDRP];

    const int t = threadIdx.x;
    const int l = t & 63, w = t >> 6;
    const int flat = blockIdx.y * 32 + blockIdx.x;          // 0..1023
    const int tau = (flat & 7) * 128 + (flat >> 3);
    const int q0 = (tau & 31) * 64;
    const int bh = tau >> 5;
    const int b = bh >> 4, h = bh & 15;
    const size_t qrow0 = (size_t)b * 2048 + q0;

    const u16* Qb_h = Qh + qrow0 * 1024 + h * 64;
    const u16* Qb_l = Ql + qrow0 * 1024 + h * 64;
    const u16* Kb_h = Kh + (size_t)b * 2048 * 1024 + h * 64;
    const u16* Vb_h = VTh + (size_t)bh * 64 * 2048;

    const int fr = l & 15;
    const int fk = (l >> 4) * 8;

    bf16x8 aqh[2], aql[2];
#pragma unroll
    for (int ks = 0; ks < 2; ++ks) {
        const size_t qo = (size_t)(w * 16 + fr) * 1024 + ks * 32 + fk;
        aqh[ks] = g8(Qb_h + qo);
        aql[ks] = g8(Qb_l + qo);
    }

    bf16x8 vone;
#pragma unroll
    for (int j = 0; j < 8; ++j) vone[j] = (short)0x3F80;

    f32x4 aco[4];
    f32x4 acl = (f32x4){0.f, 0.f, 0.f, 0.f};
#pragma unroll
    for (int m = 0; m < 4; ++m) aco[m] = (f32x4){0.f, 0.f, 0.f, 0.f};

    const int sr = t >> 3, sc = (t & 7) * 8;  // staging: row sr(+32), col sc
    bf16x8 rKh[2], rVh[2];
    auto load_kv = [&](int tt) {
        const int kv0 = tt * 64;
#pragma unroll
        for (int i = 0; i < 2; ++i) {
            const int r2 = sr + i * 32;
            rKh[i] = g8(Kb_h + (size_t)(kv0 + r2) * 1024 + sc);
            rVh[i] = g8(Vb_h + (size_t)r2 * 2048 + kv0 + sc);
        }
    };
    // swizzled LDS staging offsets (16B-aligned, XOR row&7 into slot bits)
    int soff[2];
#pragma unroll
    for (int i = 0; i < 2; ++i) {
        const int r2 = sr + i * 32;
        soff[i] = r2 * 64 + (sc ^ ((r2 & 7) << 3));
    }
    const int rswz = (fr & 7) << 3;

    load_kv(0);
    for (int tt = 0; tt < 32; ++tt) {
        __syncthreads();
#pragma unroll
        for (int i = 0; i < 2; ++i) {
            *reinterpret_cast<bf16x8*>(&sKh[soff[i]]) = rKh[i];
            *reinterpret_cast<bf16x8*>(&sVh[soff[i]]) = rVh[i];
        }
        __syncthreads();
        if (tt < 31) load_kv(tt + 1);

        // ---- QK^T: (Qh + Ql) * Kh, acc pre-biased with -12*log2e ----
        f32x4 s[4];
#pragma unroll
        for (int n = 0; n < 4; ++n) {
            s[n] = (f32x4){-SM_M2, -SM_M2, -SM_M2, -SM_M2};
#pragma unroll
            for (int ks = 0; ks < 2; ++ks) {
                bf16x8 bkh = *reinterpret_cast<const bf16x8*>(
                    &sKh[(n * 16 + fr) * 64 + ((ks * 32 + fk) ^ rswz)]);
                s[n] = __builtin_amdgcn_mfma_f32_16x16x32_bf16(aqh[ks], bkh, s[n], 0, 0, 0);
                s[n] = __builtin_amdgcn_mfma_f32_16x16x32_bf16(aql[ks], bkh, s[n], 0, 0, 0);
            }
        }

        // ---- P = exp2(s), straight to LDS ----
#pragma unroll
        for (int n = 0; n < 4; ++n)
#pragma unroll
            for (int r = 0; r < 4; ++r) {
                const float p = fast_exp2(s[n][r]);
                const int off = (w * 16 + (l >> 4) * 4 + r) * LDRP + n * 16 + (l & 15);
                sPh[off] = f2bf(p);
            }

        // ---- PV: O^T += Vh * P^T ; l += ones * P^T ----
        bf16x8 bph[2];
#pragma unroll
        for (int ks = 0; ks < 2; ++ks)
            bph[ks] = *reinterpret_cast<const bf16x8*>(&sPh[(w * 16 + fr) * LDRP + ks * 32 + fk]);
#pragma unroll
        for (int m = 0; m < 4; ++m)
#pragma unroll
            for (int ks = 0; ks < 2; ++ks) {
                bf16x8 avh = *reinterpret_cast<const bf16x8*>(
                    &sVh[(m * 16 + fr) * 64 + ((ks * 32 + fk) ^ rswz)]);
                aco[m] = __builtin_amdgcn_mfma_f32_16x16x32_bf16(avh, bph[ks], aco[m], 0, 0, 0);
            }
#pragma unroll
        for (int ks = 0; ks < 2; ++ks)
            acl = __builtin_amdgcn_mfma_f32_16x16x32_bf16(vone, bph[ks], acl, 0, 0, 0);
    }

    const float inv = 1.0f / acl[0];
#pragma unroll
    for (int m = 0; m < 4; ++m) aco[m] *= inv;

    // two-pass transpose O^T[d][q] -> O[q][d] via [32][68] fp32 region over
    // sPh (8704 B, exact fit; dead after last PV read, barrier-protected).
    float* Ol = reinterpret_cast<float*>(sPh);
    const int myq = w * 16 + (l & 15);
#pragma unroll
    for (int p = 0; p < 2; ++p) {
        __syncthreads();
        if ((w >> 1) == p) {
            const int qr = myq - p * 32;
#pragma unroll
            for (int m = 0; m < 4; ++m)
#pragma unroll
                for (int r = 0; r < 4; ++r)
                    Ol[qr * 68 + m * 16 + (l >> 4) * 4 + r] = aco[m][r];
        }
        __syncthreads();
        {
            const int qr = t >> 3, cb = (t & 7) * 8;
            const float* srcp = &Ol[qr * 68 + cb];
            u16x8 oh, olo;
#pragma unroll
            for (int j = 0; j < 8; ++j) {
                u16 hi, lo;
                split2(srcp[j], hi, lo);
                oh[j] = hi; olo[j] = lo;
            }
            const size_t ob = (qrow0 + p * 32 + qr) * 1024 + h * 64 + cb;
            *reinterpret_cast<u16x8*>(&AOh[ob]) = oh;
            *reinterpret_cast<u16x8*>(&AOl[ob]) = olo;
        }
    }
}

// ---------------- host ----------------
extern "C" void kernel_launch(void* const* d_in, const int* in_sizes, int n_in,
                              void* d_out, int out_size, void* d_ws, size_t ws_size,
                              hipStream_t stream) {
    const float* q = (const float*)d_in[0];
    const float* k = (const float*)d_in[1];
    const float* v = (const float*)d_in[2];
    const float* Wq = (const float*)d_in[3];
    const float* bq = (const float*)d_in[4];
    const float* Wk = (const float*)d_in[5];
    const float* bk = (const float*)d_in[6];
    const float* Wv = (const float*)d_in[7];
    const float* bv = (const float*)d_in[8];
    const float* Wo = (const float*)d_in[9];
    const float* bo = (const float*)d_in[10];
    const float* phase = (const float*)d_in[11];
    float* out = (float*)d_out;

    char* ws = (char*)d_ws;
    const size_t MB = 1u << 20;
    u16* Wq_h = (u16*)(ws + 0 * MB);
    u16* Wk_h = (u16*)(ws + 2 * MB);
    u16* Wv_h = (u16*)(ws + 4 * MB);
    u16* Wo_h = (u16*)(ws + 6 * MB);
    u16* q_h = (u16*)(ws + 16 * MB);
    u16* q_l = (u16*)(ws + 24 * MB);
    u16* k_h = (u16*)(ws + 32 * MB);
    u16* k_l = (u16*)(ws + 40 * MB);
    u16* v_h = (u16*)(ws + 48 * MB);
    u16* v_l = (u16*)(ws + 56 * MB);
    u16* QR_h = (u16*)(ws + 64 * MB);
    u16* QR_l = (u16*)(ws + 72 * MB);
    u16* KR_h = (u16*)(ws + 80 * MB);
    u16* VT_h = (u16*)(ws + 96 * MB);  // written by z==2 epilogue; disjoint
                                        // from v splits it reads
    u16* AO_h = (u16*)(ws + 16 * MB);   // over q splits (dead after QKV GEMM)
    u16* AO_l = (u16*)(ws + 24 * MB);

    // 1. merged splits (one launch)
    k_split<<<dim3(4096, 4), 256, 0, stream>>>(
        q, k, v, Wq, Wk, Wv, Wo,
        q_h, q_l, k_h, k_l, v_h, v_l, Wq_h, Wk_h, Wv_h, Wo_h);
    // 2. fused QKV projections (z=0,1,2); V-proj writes V^T directly
    k_gemm<<<dim3(8, 32, 3), 256, 0, stream>>>(
        q_h, q_l, k_h, k_l, v_h, v_l, AO_h, AO_l,
        Wq_h, Wk_h, Wv_h, Wo_h,
        bq, bk, bv, bo, phase, QR_h, QR_l, KR_h, VT_h, out, 0);
    // 3. attention
    k_attn<<<dim3(32, 32), 256, 0, stream>>>(QR_h, QR_l, KR_h, VT_h, AO_h, AO_l);
    // 4. output projection (z=3)
    k_gemm<<<dim3(8, 32, 1), 256, 0, stream>>>(
        q_h, q_l, k_h, k_l, v_h, v_l, AO_h, AO_l,
        Wq_h, Wk_h, Wv_h, Wo_h,
        bq, bk, bv, bo, phase, QR_h, QR_l, KR_h, VT_h, out, 3);
    (void)in_sizes; (void)n_in; (void)out_size; (void)ws_size;
}

// Round 12
// 186.624 us; speedup vs baseline: 1.1775x; 1.0078x over previous
//
#include <hip/hip_runtime.h>
#include <hip/hip_bf16.h>

// PhaseSynchronizedAttention: B=2 S=2048 D=1024 H=16 DK=64, fp32 in/out.
// Round 12: k_attn double-buffered K/V -> ONE barrier per kv-tile (was 2).
// LDS exactly 40KB = 4 blocks/CU (grid is 4 blocks/CU of work). P shrunk to
// [64][64] with the same XOR swizzle; epilogue Ol = [32][64] fp32 swizzled.
// All numerics identical to R11 (absmax should stay 9.765625e-4).

typedef short bf16x8 __attribute__((ext_vector_type(8)));
typedef float f32x4 __attribute__((ext_vector_type(4)));
typedef unsigned short u16;
typedef unsigned short u16x8 __attribute__((ext_vector_type(8)));
typedef unsigned short u16x4 __attribute__((ext_vector_type(4)));

static __device__ __forceinline__ u16 f2bf(float x) {
    __hip_bfloat16 b = __float2bfloat16(x);
    return *reinterpret_cast<u16*>(&b);
}
static __device__ __forceinline__ float bf2f(u16 u) {
    __hip_bfloat16 b = *reinterpret_cast<__hip_bfloat16*>(&u);
    return __bfloat162float(b);
}
static __device__ __forceinline__ void split2(float x, u16& hi, u16& lo) {
    hi = f2bf(x);
    lo = f2bf(x - bf2f(hi));
}
static __device__ __forceinline__ bf16x8 g8(const u16* p) {
    return *reinterpret_cast<const bf16x8*>(p);
}
static __device__ __forceinline__ float fast_exp2(float x) {
#if __has_builtin(__builtin_amdgcn_exp2f)
    return __builtin_amdgcn_exp2f(x);
#else
    return exp2f(x);
#endif
}

// ---------------- merged split: y=0,1,2 -> q,k,v (hi+lo); y=3 -> W's (hi) --
__global__ void k_split(const float* __restrict__ q, const float* __restrict__ k,
                        const float* __restrict__ v,
                        const float* __restrict__ w0, const float* __restrict__ w1,
                        const float* __restrict__ w2, const float* __restrict__ w3,
                        u16* __restrict__ qh, u16* __restrict__ ql,
                        u16* __restrict__ kh, u16* __restrict__ kl,
                        u16* __restrict__ vh, u16* __restrict__ vl,
                        u16* __restrict__ h0, u16* __restrict__ h1,
                        u16* __restrict__ h2, u16* __restrict__ h3) {
    const int i = blockIdx.x * 256 + threadIdx.x;  // grid.x = 4096 -> i < 1048576
    if (blockIdx.y == 3) {
        const int which = i >> 18;
        const int off = i & 262143;
        const float* s = (which == 0) ? w0 : (which == 1) ? w1 : (which == 2) ? w2 : w3;
        u16* H = (which == 0) ? h0 : (which == 1) ? h1 : (which == 2) ? h2 : h3;
        float4 val = reinterpret_cast<const float4*>(s)[off];
        u16x4 h;
        h[0] = f2bf(val.x);
        h[1] = f2bf(val.y);
        h[2] = f2bf(val.z);
        h[3] = f2bf(val.w);
        reinterpret_cast<u16x4*>(H)[off] = h;
        return;
    }
    const float* s;
    u16 *H, *L;
    if (blockIdx.y == 0) { s = q; H = qh; L = ql; }
    else if (blockIdx.y == 1) { s = k; H = kh; L = kl; }
    else { s = v; H = vh; L = vl; }
    float4 val = reinterpret_cast<const float4*>(s)[i];
    u16x4 h, l;
    u16 th, tl2;
    split2(val.x, th, tl2); h[0] = th; l[0] = tl2;
    split2(val.y, th, tl2); h[1] = th; l[1] = tl2;
    split2(val.z, th, tl2); h[2] = th; l[2] = tl2;
    split2(val.w, th, tl2); h[3] = th; l[3] = tl2;
    reinterpret_cast<u16x4*>(H)[i] = h;
    reinterpret_cast<u16x4*>(L)[i] = l;
}

// ---------------- unified GEMM: C[M,1024] = (Ah+Al) @ Bh^T + bias ---------
// z: 0=Q-proj(rotate, scale incl. log2e, split out), 1=K-proj(rotate,hi out),
// 2=V-proj(fused transpose -> V^T[bh][d][s] bf16), 3=out-proj(fp32 out).
// XCD swizzle: tau=(flat%8)*32+flat/8.
#define LDP 40  // padded LDS row in elems (80 B)
__global__ __launch_bounds__(256) void k_gemm(
    const u16* __restrict__ qh, const u16* __restrict__ ql,
    const u16* __restrict__ kh, const u16* __restrict__ kl,
    const u16* __restrict__ vh, const u16* __restrict__ vl,
    const u16* __restrict__ aoh, const u16* __restrict__ aol,
    const u16* __restrict__ Wqh, const u16* __restrict__ Wkh,
    const u16* __restrict__ Wvh, const u16* __restrict__ Woh,
    const float* __restrict__ bq, const float* __restrict__ bk,
    const float* __restrict__ bv_, const float* __restrict__ bo,
    const float* __restrict__ phase,
    u16* __restrict__ Qrh, u16* __restrict__ Qrl,
    u16* __restrict__ Krh,
    u16* __restrict__ VTh, float* __restrict__ outp, int zoff) {
    __shared__ __attribute__((aligned(16))) u16 sAh[128 * LDP];
    __shared__ __attribute__((aligned(16))) u16 sAl[128 * LDP];
    __shared__ __attribute__((aligned(16))) u16 sBh[128 * LDP];

    const int z = blockIdx.z + zoff;
    const u16 *Ah, *Al, *Bh;
    const float* bias;
    if (z == 0) { Ah = qh; Al = ql; Bh = Wqh; bias = bq; }
    else if (z == 1) { Ah = kh; Al = kl; Bh = Wkh; bias = bk; }
    else if (z == 2) { Ah = vh; Al = vl; Bh = Wvh; bias = bv_; }
    else { Ah = aoh; Al = aol; Bh = Woh; bias = bo; }

    const int flat = blockIdx.y * 8 + blockIdx.x;           // 0..255
    const int tau = (flat & 7) * 32 + (flat >> 3);          // bijective
    const int bx = tau & 7, by = tau >> 3;

    const int t = threadIdx.x;
    const int l = t & 63, w = t >> 6;
    const int wr = w >> 1, wc = w & 1;
    const int m0 = by * 128, n0 = bx * 128;

    const int srow = t >> 2;
    const int scol = (t & 3) * 8;
    const u16* pA0h = Ah + (size_t)(m0 + srow) * 1024 + scol;
    const u16* pA1h = Ah + (size_t)(m0 + 64 + srow) * 1024 + scol;
    const u16* pA0l = Al + (size_t)(m0 + srow) * 1024 + scol;
    const u16* pA1l = Al + (size_t)(m0 + 64 + srow) * 1024 + scol;
    const u16* pB0h = Bh + (size_t)(n0 + srow) * 1024 + scol;
    const u16* pB1h = Bh + (size_t)(n0 + 64 + srow) * 1024 + scol;
    const int so0 = srow * LDP + scol;
    const int so1 = (srow + 64) * LDP + scol;

    bf16x8 rA0h, rA1h, rA0l, rA1l, rB0h, rB1h;
    auto load_tiles = [&](int kk) {
        const int ko = kk * 32;
        rA0h = g8(pA0h + ko); rA1h = g8(pA1h + ko);
        rA0l = g8(pA0l + ko); rA1l = g8(pA1l + ko);
        rB0h = g8(pB0h + ko); rB1h = g8(pB1h + ko);
    };

    f32x4 acc[4][4];
#pragma unroll
    for (int m = 0; m < 4; ++m)
#pragma unroll
        for (int n = 0; n < 4; ++n) acc[m][n] = (f32x4){0.f, 0.f, 0.f, 0.f};

    const int fr = l & 15;
    const int fk = (l >> 4) * 8;
    const int ar = wr * 64 + fr;
    const int br = wc * 64 + fr;

    load_tiles(0);
    for (int kk = 0; kk < 32; ++kk) {
        __syncthreads();
        *reinterpret_cast<bf16x8*>(&sAh[so0]) = rA0h;
        *reinterpret_cast<bf16x8*>(&sAh[so1]) = rA1h;
        *reinterpret_cast<bf16x8*>(&sAl[so0]) = rA0l;
        *reinterpret_cast<bf16x8*>(&sAl[so1]) = rA1l;
        *reinterpret_cast<bf16x8*>(&sBh[so0]) = rB0h;
        *reinterpret_cast<bf16x8*>(&sBh[so1]) = rB1h;
        __syncthreads();
        if (kk < 31) load_tiles(kk + 1);

        bf16x8 fa_h[4], fa_l[4], fb_h[4];
#pragma unroll
        for (int m = 0; m < 4; ++m) {
            fa_h[m] = *reinterpret_cast<const bf16x8*>(&sAh[(ar + m * 16) * LDP + fk]);
            fa_l[m] = *reinterpret_cast<const bf16x8*>(&sAl[(ar + m * 16) * LDP + fk]);
        }
#pragma unroll
        for (int n = 0; n < 4; ++n)
            fb_h[n] = *reinterpret_cast<const bf16x8*>(&sBh[(br + n * 16) * LDP + fk]);
#pragma unroll
        for (int m = 0; m < 4; ++m)
#pragma unroll
            for (int n = 0; n < 4; ++n) {
                acc[m][n] = __builtin_amdgcn_mfma_f32_16x16x32_bf16(fa_h[m], fb_h[n], acc[m][n], 0, 0, 0);
                acc[m][n] = __builtin_amdgcn_mfma_f32_16x16x32_bf16(fa_l[m], fb_h[n], acc[m][n], 0, 0, 0);
            }
    }

    const int er4 = (l >> 4) * 4;
    float bvv[4];
#pragma unroll
    for (int n = 0; n < 4; ++n) bvv[n] = bias[n0 + wc * 64 + n * 16 + fr];

    if (z == 3) {
#pragma unroll
        for (int m = 0; m < 4; ++m)
#pragma unroll
            for (int n = 0; n < 4; ++n) {
                const int col = n0 + wc * 64 + n * 16 + fr;
                const size_t rb = (size_t)(m0 + wr * 64 + m * 16 + er4) * 1024 + col;
#pragma unroll
                for (int r = 0; r < 4; ++r) outp[rb + (size_t)r * 1024] = acc[m][n][r] + bvv[n];
            }
    } else if (z == 2) {
        // fused transpose: V^T[(b*16+h)*64+d][s], 4 consecutive s per thread
#pragma unroll
        for (int m = 0; m < 4; ++m) {
            const int row0 = m0 + wr * 64 + m * 16 + er4;  // s-base (mult of 4)
            const int bb = row0 >> 11;
            const int ss = row0 & 2047;
#pragma unroll
            for (int n = 0; n < 4; ++n) {
                const int col = n0 + wc * 64 + n * 16 + fr;
                const int hh_ = col >> 6, dd = col & 63;
                u16x4 vv;
#pragma unroll
                for (int r = 0; r < 4; ++r) vv[r] = f2bf(acc[m][n][r] + bvv[n]);
                *reinterpret_cast<u16x4*>(
                    &VTh[((size_t)(bb * 16 + hh_) * 64 + dd) * 2048 + ss]) = vv;
            }
        }
    } else {
        // bias + phase rotation + scale + bf16 store.
        u16* Dh = z ? Krh : Qrh;
        u16* Dl = Qrl;  // only used when z==0
        const float sc = z ? 1.0f : 0.18033688011112042f;  // (1/8)*log2(e)
        const int head = bx * 2 + wc;
        float sv, cv;
        sincosf(phase[head], &sv, &cv);
#pragma unroll
        for (int m = 0; m < 4; ++m)
#pragma unroll
            for (int n = 0; n < 2; ++n) {
#pragma unroll
                for (int r = 0; r < 4; ++r) {
                    const float xr = acc[m][n][r] + bvv[n];
                    const float xi = acc[m][n + 2][r] + bvv[n + 2];
                    const float o0 = (xr * cv - xi * sv) * sc;
                    const float o1 = (xr * sv + xi * cv) * sc;
                    const int row = m0 + wr * 64 + m * 16 + er4 + r;
                    const size_t i0 = (size_t)row * 1024 + head * 64 + n * 16 + fr;
                    u16 hh, ll;
                    split2(o0, hh, ll);
                    Dh[i0] = hh;
                    if (z == 0) Dl[i0] = ll;
                    split2(o1, hh, ll);
                    Dh[i0 + 32] = hh;
                    if (z == 0) Dl[i0 + 32] = ll;
                }
            }
    }
}

// ---------------- flash attention (fixed-max softmax, exp2, K/V dbuf) -----
// grid flat = 1024; XCD swizzle. Wave w owns q rows w*16..+15.
// S' = S*log2e via pre-scaled Q; acc init = -12*log2e; P = exp2(s).
// K/V double-buffered [64*64] u16 arrays, XOR swizzle idx ^= (row&7)<<3.
// ONE barrier per kv-tile. P[64][64] swizzled, wave-private (no barrier).
#define SM_M2 17.312340490667562f  // 12 * log2(e)

#define ATTN_TILE(SK, SV)                                                      \
  {                                                                            \
    f32x4 s[4];                                                                \
    _Pragma("unroll") for (int n = 0; n < 4; ++n) {                            \
      s[n] = (f32x4){-SM_M2, -SM_M2, -SM_M2, -SM_M2};                          \
      _Pragma("unroll") for (int ks = 0; ks < 2; ++ks) {                       \
        bf16x8 bkh = *reinterpret_cast<const bf16x8*>(                         \
            &SK[(n * 16 + fr) * 64 + ((ks * 32 + fk) ^ rswz)]);                \
        s[n] = __builtin_amdgcn_mfma_f32_16x16x32_bf16(aqh[ks], bkh, s[n], 0, 0, 0); \
        s[n] = __builtin_amdgcn_mfma_f32_16x16x32_bf16(aql[ks], bkh, s[n], 0, 0, 0); \
      }                                                                        \
    }                                                                          \
    _Pragma("unroll") for (int n = 0; n < 4; ++n)                              \
      _Pragma("unroll") for (int r = 0; r < 4; ++r) {                          \
        const float p = fast_exp2(s[n][r]);                                    \
        const int prow = w * 16 + (l >> 4) * 4 + r;                            \
        const int pcol = (n * 16 + (l & 15)) ^ ((prow & 7) << 3);              \
        sPh[prow * 64 + pcol] = f2bf(p);                                       \
      }                                                                        \
    bf16x8 bph[2];                                                             \
    _Pragma("unroll") for (int ks = 0; ks < 2; ++ks)                           \
      bph[ks] = *reinterpret_cast<const bf16x8*>(                              \
          &sPh[(w * 16 + fr) * 64 + ((ks * 32 + fk) ^ rswz)]);                 \
    _Pragma("unroll") for (int m = 0; m < 4; ++m)                              \
      _Pragma("unroll") for (int ks = 0; ks < 2; ++ks) {                       \
        bf16x8 avh = *reinterpret_cast<const bf16x8*>(                         \
            &SV[(m * 16 + fr) * 64 + ((ks * 32 + fk) ^ rswz)]);                \
        aco[m] = __builtin_amdgcn_mfma_f32_16x16x32_bf16(avh, bph[ks], aco[m], 0, 0, 0); \
      }                                                                        \
    _Pragma("unroll") for (int ks = 0; ks < 2; ++ks)                           \
      acl = __builtin_amdgcn_mfma_f32_16x16x32_bf16(vone, bph[ks], acl, 0, 0, 0); \
  }

#define ATTN_STAGE(SK, SV)                                                     \
  {                                                                            \
    _Pragma("unroll") for (int i = 0; i < 2; ++i) {                            \
      *reinterpret_cast<bf16x8*>(&SK[soff[i]]) = rKh[i];                       \
      *reinterpret_cast<bf16x8*>(&SV[soff[i]]) = rVh[i];                       \
    }                                                                          \
  }

__global__ __launch_bounds__(256) void k_attn(
    const u16* __restrict__ Qh, const u16* __restrict__ Ql,
    const u16* __restrict__ Kh,
    const u16* __restrict__ VTh,
    u16* __restrict__ AOh, u16* __restrict__ AOl) {
    __shared__ __attribute__((aligned(16))) u16 sK0[4096];
    __shared__ __attribute__((aligned(16))) u16 sK1[4096];
    __shared__ __attribute__((aligned(16))) u16 sV0[4096];
    __shared__ __attribute__((aligned(16))) u16 sV1[4096];
    __shared__ __attribute__((aligned(16))) u16 sPh[4096];

    const int t = threadIdx.x;
    const int l = t & 63, w = t >> 6;
    const int flat = blockIdx.y * 32 + blockIdx.x;          // 0..1023
    const int tau = (flat & 7) * 128 + (flat >> 3);
    const int q0 = (tau & 31) * 64;
    const int bh = tau >> 5;
    const int b = bh >> 4, h = bh & 15;
    const size_t qrow0 = (size_t)b * 2048 + q0;

    const u16* Qb_h = Qh + qrow0 * 1024 + h * 64;
    const u16* Qb_l = Ql + qrow0 * 1024 + h * 64;
    const u16* Kb_h = Kh + (size_t)b * 2048 * 1024 + h * 64;
    const u16* Vb_h = VTh + (size_t)bh * 64 * 2048;

    const int fr = l & 15;
    const int fk = (l >> 4) * 8;

    bf16x8 aqh[2], aql[2];
#pragma unroll
    for (int ks = 0; ks < 2; ++ks) {
        const size_t qo = (size_t)(w * 16 + fr) * 1024 + ks * 32 + fk;
        aqh[ks] = g8(Qb_h + qo);
        aql[ks] = g8(Qb_l + qo);
    }

    bf16x8 vone;
#pragma unroll
    for (int j = 0; j < 8; ++j) vone[j] = (short)0x3F80;

    f32x4 aco[4];
    f32x4 acl = (f32x4){0.f, 0.f, 0.f, 0.f};
#pragma unroll
    for (int m = 0; m < 4; ++m) aco[m] = (f32x4){0.f, 0.f, 0.f, 0.f};

    const int sr = t >> 3, sc = (t & 7) * 8;  // staging: row sr(+32), col sc
    bf16x8 rKh[2], rVh[2];
    auto load_kv = [&](int tt) {
        const int kv0 = tt * 64;
#pragma unroll
        for (int i = 0; i < 2; ++i) {
            const int r2 = sr + i * 32;
            rKh[i] = g8(Kb_h + (size_t)(kv0 + r2) * 1024 + sc);
            rVh[i] = g8(Vb_h + (size_t)r2 * 2048 + kv0 + sc);
        }
    };
    int soff[2];
#pragma unroll
    for (int i = 0; i < 2; ++i) {
        const int r2 = sr + i * 32;
        soff[i] = r2 * 64 + (sc ^ ((r2 & 7) << 3));
    }
    const int rswz = (fr & 7) << 3;

    // prologue: stage tile 0 into buf0
    load_kv(0);
    ATTN_STAGE(sK0, sV0);
    __syncthreads();

    for (int tt = 0; tt < 32; tt += 2) {
        // even tile: compute buf0, stage tile tt+1 into buf1
        load_kv(tt + 1);  // tt <= 30, always valid
        ATTN_TILE(sK0, sV0);
        ATTN_STAGE(sK1, sV1);
        __syncthreads();
        // odd tile: compute buf1, stage tile tt+2 into buf0
        if (tt + 2 < 32) load_kv(tt + 2);
        ATTN_TILE(sK1, sV1);
        if (tt + 2 < 32) ATTN_STAGE(sK0, sV0);
        __syncthreads();
    }

    const float inv = 1.0f / acl[0];
#pragma unroll
    for (int m = 0; m < 4; ++m) aco[m] *= inv;

    // two-pass transpose O^T[d][q] -> O[q][d] via swizzled [32][64] fp32
    // region over sPh (8192 B exact), then coalesced split store.
    float* Ol = reinterpret_cast<float*>(sPh);
    const int myq = w * 16 + (l & 15);
#pragma unroll
    for (int p = 0; p < 2; ++p) {
        __syncthreads();
        if ((w >> 1) == p) {
            const int qr = myq - p * 32;
            const int sw = (qr & 7) << 3;
#pragma unroll
            for (int m = 0; m < 4; ++m)
#pragma unroll
                for (int r = 0; r < 4; ++r)
                    Ol[qr * 64 + ((m * 16 + (l >> 4) * 4 + r) ^ sw)] = aco[m][r];
        }
        __syncthreads();
        {
            const int qr = t >> 3, cb = (t & 7) * 8;
            const int sw = (qr & 7) << 3;
            const float* srcp = &Ol[qr * 64 + (cb ^ sw)];
            u16x8 oh, olo;
#pragma unroll
            for (int j = 0; j < 8; ++j) {
                u16 hi, lo;
                split2(srcp[j], hi, lo);
                oh[j] = hi; olo[j] = lo;
            }
            const size_t ob = (qrow0 + p * 32 + qr) * 1024 + h * 64 + cb;
            *reinterpret_cast<u16x8*>(&AOh[ob]) = oh;
            *reinterpret_cast<u16x8*>(&AOl[ob]) = olo;
        }
    }
}

// ---------------- host ----------------
extern "C" void kernel_launch(void* const* d_in, const int* in_sizes, int n_in,
                              void* d_out, int out_size, void* d_ws, size_t ws_size,
                              hipStream_t stream) {
    const float* q = (const float*)d_in[0];
    const float* k = (const float*)d_in[1];
    const float* v = (const float*)d_in[2];
    const float* Wq = (const float*)d_in[3];
    const float* bq = (const float*)d_in[4];
    const float* Wk = (const float*)d_in[5];
    const float* bk = (const float*)d_in[6];
    const float* Wv = (const float*)d_in[7];
    const float* bv = (const float*)d_in[8];
    const float* Wo = (const float*)d_in[9];
    const float* bo = (const float*)d_in[10];
    const float* phase = (const float*)d_in[11];
    float* out = (float*)d_out;

    char* ws = (char*)d_ws;
    const size_t MB = 1u << 20;
    u16* Wq_h = (u16*)(ws + 0 * MB);
    u16* Wk_h = (u16*)(ws + 2 * MB);
    u16* Wv_h = (u16*)(ws + 4 * MB);
    u16* Wo_h = (u16*)(ws + 6 * MB);
    u16* q_h = (u16*)(ws + 16 * MB);
    u16* q_l = (u16*)(ws + 24 * MB);
    u16* k_h = (u16*)(ws + 32 * MB);
    u16* k_l = (u16*)(ws + 40 * MB);
    u16* v_h = (u16*)(ws + 48 * MB);
    u16* v_l = (u16*)(ws + 56 * MB);
    u16* QR_h = (u16*)(ws + 64 * MB);
    u16* QR_l = (u16*)(ws + 72 * MB);
    u16* KR_h = (u16*)(ws + 80 * MB);
    u16* VT_h = (u16*)(ws + 96 * MB);  // z==2 epilogue output; disjoint from
                                        // the v splits its blocks read
    u16* AO_h = (u16*)(ws + 16 * MB);   // over q splits (dead after QKV GEMM)
    u16* AO_l = (u16*)(ws + 24 * MB);

    // 1. merged splits (one launch)
    k_split<<<dim3(4096, 4), 256, 0, stream>>>(
        q, k, v, Wq, Wk, Wv, Wo,
        q_h, q_l, k_h, k_l, v_h, v_l, Wq_h, Wk_h, Wv_h, Wo_h);
    // 2. fused QKV projections (z=0,1,2); V-proj writes V^T directly
    k_gemm<<<dim3(8, 32, 3), 256, 0, stream>>>(
        q_h, q_l, k_h, k_l, v_h, v_l, AO_h, AO_l,
        Wq_h, Wk_h, Wv_h, Wo_h,
        bq, bk, bv, bo, phase, QR_h, QR_l, KR_h, VT_h, out, 0);
    // 3. attention
    k_attn<<<dim3(32, 32), 256, 0, stream>>>(QR_h, QR_l, KR_h, VT_h, AO_h, AO_l);
    // 4. output projection (z=3)
    k_gemm<<<dim3(8, 32, 1), 256, 0, stream>>>(
        q_h, q_l, k_h, k_l, v_h, v_l, AO_h, AO_l,
        Wq_h, Wk_h, Wv_h, Wo_h,
        bq, bk, bv, bo, phase, QR_h, QR_l, KR_h, VT_h, out, 3);
    (void)in_sizes; (void)n_in; (void)out_size; (void)ws_size;
}

// Round 13
// 182.658 us; speedup vs baseline: 1.2030x; 1.0217x over previous
//
#include <hip/hip_runtime.h>
#include <hip/hip_bf16.h>

// PhaseSynchronizedAttention: B=2 S=2048 D=1024 H=16 DK=64, fp32 in/out.
// Round 13: k_attn QBLK 64 -> 128 (each wave owns 32 q-rows as 2 fragments).
// MFMA/tile/wave 26 -> 52 while staging+barriers+K/V traffic per unit work
// halve. K-frag (bkh) and V-frag (avh) LDS reads shared across both q-subtiles.
// All numerics identical (absmax should stay 9.765625e-4).

typedef short bf16x8 __attribute__((ext_vector_type(8)));
typedef float f32x4 __attribute__((ext_vector_type(4)));
typedef unsigned short u16;
typedef unsigned short u16x8 __attribute__((ext_vector_type(8)));
typedef unsigned short u16x4 __attribute__((ext_vector_type(4)));

static __device__ __forceinline__ u16 f2bf(float x) {
    __hip_bfloat16 b = __float2bfloat16(x);
    return *reinterpret_cast<u16*>(&b);
}
static __device__ __forceinline__ float bf2f(u16 u) {
    __hip_bfloat16 b = *reinterpret_cast<__hip_bfloat16*>(&u);
    return __bfloat162float(b);
}
static __device__ __forceinline__ void split2(float x, u16& hi, u16& lo) {
    hi = f2bf(x);
    lo = f2bf(x - bf2f(hi));
}
static __device__ __forceinline__ bf16x8 g8(const u16* p) {
    return *reinterpret_cast<const bf16x8*>(p);
}
static __device__ __forceinline__ float fast_exp2(float x) {
#if __has_builtin(__builtin_amdgcn_exp2f)
    return __builtin_amdgcn_exp2f(x);
#else
    return exp2f(x);
#endif
}

// ---------------- merged split: y=0,1,2 -> q,k,v (hi+lo); y=3 -> W's (hi) --
__global__ void k_split(const float* __restrict__ q, const float* __restrict__ k,
                        const float* __restrict__ v,
                        const float* __restrict__ w0, const float* __restrict__ w1,
                        const float* __restrict__ w2, const float* __restrict__ w3,
                        u16* __restrict__ qh, u16* __restrict__ ql,
                        u16* __restrict__ kh, u16* __restrict__ kl,
                        u16* __restrict__ vh, u16* __restrict__ vl,
                        u16* __restrict__ h0, u16* __restrict__ h1,
                        u16* __restrict__ h2, u16* __restrict__ h3) {
    const int i = blockIdx.x * 256 + threadIdx.x;  // grid.x = 4096 -> i < 1048576
    if (blockIdx.y == 3) {
        const int which = i >> 18;
        const int off = i & 262143;
        const float* s = (which == 0) ? w0 : (which == 1) ? w1 : (which == 2) ? w2 : w3;
        u16* H = (which == 0) ? h0 : (which == 1) ? h1 : (which == 2) ? h2 : h3;
        float4 val = reinterpret_cast<const float4*>(s)[off];
        u16x4 h;
        h[0] = f2bf(val.x);
        h[1] = f2bf(val.y);
        h[2] = f2bf(val.z);
        h[3] = f2bf(val.w);
        reinterpret_cast<u16x4*>(H)[off] = h;
        return;
    }
    const float* s;
    u16 *H, *L;
    if (blockIdx.y == 0) { s = q; H = qh; L = ql; }
    else if (blockIdx.y == 1) { s = k; H = kh; L = kl; }
    else { s = v; H = vh; L = vl; }
    float4 val = reinterpret_cast<const float4*>(s)[i];
    u16x4 h, l;
    u16 th, tl2;
    split2(val.x, th, tl2); h[0] = th; l[0] = tl2;
    split2(val.y, th, tl2); h[1] = th; l[1] = tl2;
    split2(val.z, th, tl2); h[2] = th; l[2] = tl2;
    split2(val.w, th, tl2); h[3] = th; l[3] = tl2;
    reinterpret_cast<u16x4*>(H)[i] = h;
    reinterpret_cast<u16x4*>(L)[i] = l;
}

// ---------------- unified GEMM: C[M,1024] = (Ah+Al) @ Bh^T + bias ---------
// z: 0=Q-proj(rotate, scale incl. log2e, split out), 1=K-proj(rotate,hi out),
// 2=V-proj(fused transpose -> V^T[bh][d][s] bf16), 3=out-proj(fp32 out).
// XCD swizzle: tau=(flat%8)*32+flat/8.
#define LDP 40  // padded LDS row in elems (80 B)
__global__ __launch_bounds__(256) void k_gemm(
    const u16* __restrict__ qh, const u16* __restrict__ ql,
    const u16* __restrict__ kh, const u16* __restrict__ kl,
    const u16* __restrict__ vh, const u16* __restrict__ vl,
    const u16* __restrict__ aoh, const u16* __restrict__ aol,
    const u16* __restrict__ Wqh, const u16* __restrict__ Wkh,
    const u16* __restrict__ Wvh, const u16* __restrict__ Woh,
    const float* __restrict__ bq, const float* __restrict__ bk,
    const float* __restrict__ bv_, const float* __restrict__ bo,
    const float* __restrict__ phase,
    u16* __restrict__ Qrh, u16* __restrict__ Qrl,
    u16* __restrict__ Krh,
    u16* __restrict__ VTh, float* __restrict__ outp, int zoff) {
    __shared__ __attribute__((aligned(16))) u16 sAh[128 * LDP];
    __shared__ __attribute__((aligned(16))) u16 sAl[128 * LDP];
    __shared__ __attribute__((aligned(16))) u16 sBh[128 * LDP];

    const int z = blockIdx.z + zoff;
    const u16 *Ah, *Al, *Bh;
    const float* bias;
    if (z == 0) { Ah = qh; Al = ql; Bh = Wqh; bias = bq; }
    else if (z == 1) { Ah = kh; Al = kl; Bh = Wkh; bias = bk; }
    else if (z == 2) { Ah = vh; Al = vl; Bh = Wvh; bias = bv_; }
    else { Ah = aoh; Al = aol; Bh = Woh; bias = bo; }

    const int flat = blockIdx.y * 8 + blockIdx.x;           // 0..255
    const int tau = (flat & 7) * 32 + (flat >> 3);          // bijective
    const int bx = tau & 7, by = tau >> 3;

    const int t = threadIdx.x;
    const int l = t & 63, w = t >> 6;
    const int wr = w >> 1, wc = w & 1;
    const int m0 = by * 128, n0 = bx * 128;

    const int srow = t >> 2;
    const int scol = (t & 3) * 8;
    const u16* pA0h = Ah + (size_t)(m0 + srow) * 1024 + scol;
    const u16* pA1h = Ah + (size_t)(m0 + 64 + srow) * 1024 + scol;
    const u16* pA0l = Al + (size_t)(m0 + srow) * 1024 + scol;
    const u16* pA1l = Al + (size_t)(m0 + 64 + srow) * 1024 + scol;
    const u16* pB0h = Bh + (size_t)(n0 + srow) * 1024 + scol;
    const u16* pB1h = Bh + (size_t)(n0 + 64 + srow) * 1024 + scol;
    const int so0 = srow * LDP + scol;
    const int so1 = (srow + 64) * LDP + scol;

    bf16x8 rA0h, rA1h, rA0l, rA1l, rB0h, rB1h;
    auto load_tiles = [&](int kk) {
        const int ko = kk * 32;
        rA0h = g8(pA0h + ko); rA1h = g8(pA1h + ko);
        rA0l = g8(pA0l + ko); rA1l = g8(pA1l + ko);
        rB0h = g8(pB0h + ko); rB1h = g8(pB1h + ko);
    };

    f32x4 acc[4][4];
#pragma unroll
    for (int m = 0; m < 4; ++m)
#pragma unroll
        for (int n = 0; n < 4; ++n) acc[m][n] = (f32x4){0.f, 0.f, 0.f, 0.f};

    const int fr = l & 15;
    const int fk = (l >> 4) * 8;
    const int ar = wr * 64 + fr;
    const int br = wc * 64 + fr;

    load_tiles(0);
    for (int kk = 0; kk < 32; ++kk) {
        __syncthreads();
        *reinterpret_cast<bf16x8*>(&sAh[so0]) = rA0h;
        *reinterpret_cast<bf16x8*>(&sAh[so1]) = rA1h;
        *reinterpret_cast<bf16x8*>(&sAl[so0]) = rA0l;
        *reinterpret_cast<bf16x8*>(&sAl[so1]) = rA1l;
        *reinterpret_cast<bf16x8*>(&sBh[so0]) = rB0h;
        *reinterpret_cast<bf16x8*>(&sBh[so1]) = rB1h;
        __syncthreads();
        if (kk < 31) load_tiles(kk + 1);

        bf16x8 fa_h[4], fa_l[4], fb_h[4];
#pragma unroll
        for (int m = 0; m < 4; ++m) {
            fa_h[m] = *reinterpret_cast<const bf16x8*>(&sAh[(ar + m * 16) * LDP + fk]);
            fa_l[m] = *reinterpret_cast<const bf16x8*>(&sAl[(ar + m * 16) * LDP + fk]);
        }
#pragma unroll
        for (int n = 0; n < 4; ++n)
            fb_h[n] = *reinterpret_cast<const bf16x8*>(&sBh[(br + n * 16) * LDP + fk]);
#pragma unroll
        for (int m = 0; m < 4; ++m)
#pragma unroll
            for (int n = 0; n < 4; ++n) {
                acc[m][n] = __builtin_amdgcn_mfma_f32_16x16x32_bf16(fa_h[m], fb_h[n], acc[m][n], 0, 0, 0);
                acc[m][n] = __builtin_amdgcn_mfma_f32_16x16x32_bf16(fa_l[m], fb_h[n], acc[m][n], 0, 0, 0);
            }
    }

    const int er4 = (l >> 4) * 4;
    float bvv[4];
#pragma unroll
    for (int n = 0; n < 4; ++n) bvv[n] = bias[n0 + wc * 64 + n * 16 + fr];

    if (z == 3) {
#pragma unroll
        for (int m = 0; m < 4; ++m)
#pragma unroll
            for (int n = 0; n < 4; ++n) {
                const int col = n0 + wc * 64 + n * 16 + fr;
                const size_t rb = (size_t)(m0 + wr * 64 + m * 16 + er4) * 1024 + col;
#pragma unroll
                for (int r = 0; r < 4; ++r) outp[rb + (size_t)r * 1024] = acc[m][n][r] + bvv[n];
            }
    } else if (z == 2) {
        // fused transpose: V^T[(b*16+h)*64+d][s], 4 consecutive s per thread
#pragma unroll
        for (int m = 0; m < 4; ++m) {
            const int row0 = m0 + wr * 64 + m * 16 + er4;  // s-base (mult of 4)
            const int bb = row0 >> 11;
            const int ss = row0 & 2047;
#pragma unroll
            for (int n = 0; n < 4; ++n) {
                const int col = n0 + wc * 64 + n * 16 + fr;
                const int hh_ = col >> 6, dd = col & 63;
                u16x4 vv;
#pragma unroll
                for (int r = 0; r < 4; ++r) vv[r] = f2bf(acc[m][n][r] + bvv[n]);
                *reinterpret_cast<u16x4*>(
                    &VTh[((size_t)(bb * 16 + hh_) * 64 + dd) * 2048 + ss]) = vv;
            }
        }
    } else {
        // bias + phase rotation + scale + bf16 store.
        u16* Dh = z ? Krh : Qrh;
        u16* Dl = Qrl;  // only used when z==0
        const float sc = z ? 1.0f : 0.18033688011112042f;  // (1/8)*log2(e)
        const int head = bx * 2 + wc;
        float sv, cv;
        sincosf(phase[head], &sv, &cv);
#pragma unroll
        for (int m = 0; m < 4; ++m)
#pragma unroll
            for (int n = 0; n < 2; ++n) {
#pragma unroll
                for (int r = 0; r < 4; ++r) {
                    const float xr = acc[m][n][r] + bvv[n];
                    const float xi = acc[m][n + 2][r] + bvv[n + 2];
                    const float o0 = (xr * cv - xi * sv) * sc;
                    const float o1 = (xr * sv + xi * cv) * sc;
                    const int row = m0 + wr * 64 + m * 16 + er4 + r;
                    const size_t i0 = (size_t)row * 1024 + head * 64 + n * 16 + fr;
                    u16 hh, ll;
                    split2(o0, hh, ll);
                    Dh[i0] = hh;
                    if (z == 0) Dl[i0] = ll;
                    split2(o1, hh, ll);
                    Dh[i0 + 32] = hh;
                    if (z == 0) Dl[i0 + 32] = ll;
                }
            }
    }
}

// ---------------- flash attention (QBLK=128, fixed-max, exp2, dbuf) -------
// grid flat = 512; XCD swizzle tau=(flat&7)*64+flat/8: XCD c owns heads
// [4c,4c+4). Block covers 128 q-rows; wave w owns rows w*32..w*32+31 as 2
// fragments (qm=0,1). K-frag/V-frag LDS reads shared across qm.
// P[128][64] swizzled, wave-private. K/V dbuf, 1 barrier/tile.
#define SM_M2 17.312340490667562f  // 12 * log2(e)

#define ATTN_TILE(SK, SV)                                                      \
  {                                                                            \
    f32x4 s[2][4];                                                             \
    _Pragma("unroll") for (int qm = 0; qm < 2; ++qm)                           \
      _Pragma("unroll") for (int n = 0; n < 4; ++n)                            \
        s[qm][n] = (f32x4){-SM_M2, -SM_M2, -SM_M2, -SM_M2};                    \
    _Pragma("unroll") for (int n = 0; n < 4; ++n)                              \
      _Pragma("unroll") for (int ks = 0; ks < 2; ++ks) {                       \
        bf16x8 bkh = *reinterpret_cast<const bf16x8*>(                         \
            &SK[(n * 16 + fr) * 64 + ((ks * 32 + fk) ^ rswz)]);                \
        _Pragma("unroll") for (int qm = 0; qm < 2; ++qm) {                     \
          s[qm][n] = __builtin_amdgcn_mfma_f32_16x16x32_bf16(aqh[qm][ks], bkh, s[qm][n], 0, 0, 0); \
          s[qm][n] = __builtin_amdgcn_mfma_f32_16x16x32_bf16(aql[qm][ks], bkh, s[qm][n], 0, 0, 0); \
        }                                                                      \
      }                                                                        \
    _Pragma("unroll") for (int qm = 0; qm < 2; ++qm)                           \
      _Pragma("unroll") for (int n = 0; n < 4; ++n)                            \
        _Pragma("unroll") for (int r = 0; r < 4; ++r) {                        \
          const float p = fast_exp2(s[qm][n][r]);                              \
          const int prow = w * 32 + qm * 16 + (l >> 4) * 4 + r;                \
          const int pcol = (n * 16 + (l & 15)) ^ ((prow & 7) << 3);            \
          sPh[prow * 64 + pcol] = f2bf(p);                                     \
        }                                                                      \
    bf16x8 bph[2][2];                                                          \
    _Pragma("unroll") for (int qm = 0; qm < 2; ++qm)                           \
      _Pragma("unroll") for (int ks = 0; ks < 2; ++ks)                         \
        bph[qm][ks] = *reinterpret_cast<const bf16x8*>(                        \
            &sPh[(w * 32 + qm * 16 + fr) * 64 + ((ks * 32 + fk) ^ rswz)]);     \
    _Pragma("unroll") for (int m = 0; m < 4; ++m)                              \
      _Pragma("unroll") for (int ks = 0; ks < 2; ++ks) {                       \
        bf16x8 avh = *reinterpret_cast<const bf16x8*>(                         \
            &SV[(m * 16 + fr) * 64 + ((ks * 32 + fk) ^ rswz)]);                \
        _Pragma("unroll") for (int qm = 0; qm < 2; ++qm)                       \
          aco[qm][m] = __builtin_amdgcn_mfma_f32_16x16x32_bf16(avh, bph[qm][ks], aco[qm][m], 0, 0, 0); \
      }                                                                        \
    _Pragma("unroll") for (int qm = 0; qm < 2; ++qm)                           \
      _Pragma("unroll") for (int ks = 0; ks < 2; ++ks)                         \
        acl[qm] = __builtin_amdgcn_mfma_f32_16x16x32_bf16(vone, bph[qm][ks], acl[qm], 0, 0, 0); \
  }

#define ATTN_STAGE(SK, SV)                                                     \
  {                                                                            \
    _Pragma("unroll") for (int i = 0; i < 2; ++i) {                            \
      *reinterpret_cast<bf16x8*>(&SK[soff[i]]) = rKh[i];                       \
      *reinterpret_cast<bf16x8*>(&SV[soff[i]]) = rVh[i];                       \
    }                                                                          \
  }

__global__ __launch_bounds__(256) void k_attn(
    const u16* __restrict__ Qh, const u16* __restrict__ Ql,
    const u16* __restrict__ Kh,
    const u16* __restrict__ VTh,
    u16* __restrict__ AOh, u16* __restrict__ AOl) {
    __shared__ __attribute__((aligned(16))) u16 sK0[4096];
    __shared__ __attribute__((aligned(16))) u16 sK1[4096];
    __shared__ __attribute__((aligned(16))) u16 sV0[4096];
    __shared__ __attribute__((aligned(16))) u16 sV1[4096];
    __shared__ __attribute__((aligned(16))) u16 sPh[128 * 64];

    const int t = threadIdx.x;
    const int l = t & 63, w = t >> 6;
    const int flat = blockIdx.y * 16 + blockIdx.x;          // 0..511
    const int tau = (flat & 7) * 64 + (flat >> 3);          // bijective
    const int q0 = (tau & 15) * 128;
    const int bh = tau >> 4;
    const int b = bh >> 4, h = bh & 15;
    const size_t qrow0 = (size_t)b * 2048 + q0;

    const u16* Qb_h = Qh + qrow0 * 1024 + h * 64;
    const u16* Qb_l = Ql + qrow0 * 1024 + h * 64;
    const u16* Kb_h = Kh + (size_t)b * 2048 * 1024 + h * 64;
    const u16* Vb_h = VTh + (size_t)bh * 64 * 2048;

    const int fr = l & 15;
    const int fk = (l >> 4) * 8;

    bf16x8 aqh[2][2], aql[2][2];
#pragma unroll
    for (int qm = 0; qm < 2; ++qm)
#pragma unroll
        for (int ks = 0; ks < 2; ++ks) {
            const size_t qo = (size_t)(w * 32 + qm * 16 + fr) * 1024 + ks * 32 + fk;
            aqh[qm][ks] = g8(Qb_h + qo);
            aql[qm][ks] = g8(Qb_l + qo);
        }

    bf16x8 vone;
#pragma unroll
    for (int j = 0; j < 8; ++j) vone[j] = (short)0x3F80;

    f32x4 aco[2][4];
    f32x4 acl[2];
#pragma unroll
    for (int qm = 0; qm < 2; ++qm) {
        acl[qm] = (f32x4){0.f, 0.f, 0.f, 0.f};
#pragma unroll
        for (int m = 0; m < 4; ++m) aco[qm][m] = (f32x4){0.f, 0.f, 0.f, 0.f};
    }

    const int sr = t >> 3, sc = (t & 7) * 8;  // staging: row sr(+32), col sc
    bf16x8 rKh[2], rVh[2];
    auto load_kv = [&](int tt) {
        const int kv0 = tt * 64;
#pragma unroll
        for (int i = 0; i < 2; ++i) {
            const int r2 = sr + i * 32;
            rKh[i] = g8(Kb_h + (size_t)(kv0 + r2) * 1024 + sc);
            rVh[i] = g8(Vb_h + (size_t)r2 * 2048 + kv0 + sc);
        }
    };
    int soff[2];
#pragma unroll
    for (int i = 0; i < 2; ++i) {
        const int r2 = sr + i * 32;
        soff[i] = r2 * 64 + (sc ^ ((r2 & 7) << 3));
    }
    const int rswz = (fr & 7) << 3;

    // prologue: stage tile 0 into buf0
    load_kv(0);
    ATTN_STAGE(sK0, sV0);
    __syncthreads();

    for (int tt = 0; tt < 32; tt += 2) {
        load_kv(tt + 1);
        ATTN_TILE(sK0, sV0);
        ATTN_STAGE(sK1, sV1);
        __syncthreads();
        if (tt + 2 < 32) load_kv(tt + 2);
        ATTN_TILE(sK1, sV1);
        if (tt + 2 < 32) ATTN_STAGE(sK0, sV0);
        __syncthreads();
    }

#pragma unroll
    for (int qm = 0; qm < 2; ++qm) {
        const float inv = 1.0f / acl[qm][0];
#pragma unroll
        for (int m = 0; m < 4; ++m) aco[qm][m] *= inv;
    }

    // four-pass transpose O^T[d][q] -> O[q][d] via swizzled [32][64] fp32
    // region over sPh; pass p covers q-rows [p*32, p*32+32) = wave p's rows.
    float* Ol = reinterpret_cast<float*>(sPh);
#pragma unroll
    for (int p = 0; p < 4; ++p) {
        __syncthreads();
        if (w == p) {
#pragma unroll
            for (int qm = 0; qm < 2; ++qm) {
                const int qr = qm * 16 + (l & 15);
                const int sw = (qr & 7) << 3;
#pragma unroll
                for (int m = 0; m < 4; ++m)
#pragma unroll
                    for (int r = 0; r < 4; ++r)
                        Ol[qr * 64 + ((m * 16 + (l >> 4) * 4 + r) ^ sw)] = aco[qm][m][r];
            }
        }
        __syncthreads();
        {
            const int qr = t >> 3, cb = (t & 7) * 8;
            const int sw = (qr & 7) << 3;
            const float* srcp = &Ol[qr * 64 + (cb ^ sw)];
            u16x8 oh, olo;
#pragma unroll
            for (int j = 0; j < 8; ++j) {
                u16 hi, lo;
                split2(srcp[j], hi, lo);
                oh[j] = hi; olo[j] = lo;
            }
            const size_t ob = (qrow0 + p * 32 + qr) * 1024 + h * 64 + cb;
            *reinterpret_cast<u16x8*>(&AOh[ob]) = oh;
            *reinterpret_cast<u16x8*>(&AOl[ob]) = olo;
        }
    }
}

// ---------------- host ----------------
extern "C" void kernel_launch(void* const* d_in, const int* in_sizes, int n_in,
                              void* d_out, int out_size, void* d_ws, size_t ws_size,
                              hipStream_t stream) {
    const float* q = (const float*)d_in[0];
    const float* k = (const float*)d_in[1];
    const float* v = (const float*)d_in[2];
    const float* Wq = (const float*)d_in[3];
    const float* bq = (const float*)d_in[4];
    const float* Wk = (const float*)d_in[5];
    const float* bk = (const float*)d_in[6];
    const float* Wv = (const float*)d_in[7];
    const float* bv = (const float*)d_in[8];
    const float* Wo = (const float*)d_in[9];
    const float* bo = (const float*)d_in[10];
    const float* phase = (const float*)d_in[11];
    float* out = (float*)d_out;

    char* ws = (char*)d_ws;
    const size_t MB = 1u << 20;
    u16* Wq_h = (u16*)(ws + 0 * MB);
    u16* Wk_h = (u16*)(ws + 2 * MB);
    u16* Wv_h = (u16*)(ws + 4 * MB);
    u16* Wo_h = (u16*)(ws + 6 * MB);
    u16* q_h = (u16*)(ws + 16 * MB);
    u16* q_l = (u16*)(ws + 24 * MB);
    u16* k_h = (u16*)(ws + 32 * MB);
    u16* k_l = (u16*)(ws + 40 * MB);
    u16* v_h = (u16*)(ws + 48 * MB);
    u16* v_l = (u16*)(ws + 56 * MB);
    u16* QR_h = (u16*)(ws + 64 * MB);
    u16* QR_l = (u16*)(ws + 72 * MB);
    u16* KR_h = (u16*)(ws + 80 * MB);
    u16* VT_h = (u16*)(ws + 96 * MB);  // z==2 epilogue output; disjoint from
                                        // the v splits its blocks read
    u16* AO_h = (u16*)(ws + 16 * MB);   // over q splits (dead after QKV GEMM)
    u16* AO_l = (u16*)(ws + 24 * MB);

    // 1. merged splits (one launch)
    k_split<<<dim3(4096, 4), 256, 0, stream>>>(
        q, k, v, Wq, Wk, Wv, Wo,
        q_h, q_l, k_h, k_l, v_h, v_l, Wq_h, Wk_h, Wv_h, Wo_h);
    // 2. fused QKV projections (z=0,1,2); V-proj writes V^T directly
    k_gemm<<<dim3(8, 32, 3), 256, 0, stream>>>(
        q_h, q_l, k_h, k_l, v_h, v_l, AO_h, AO_l,
        Wq_h, Wk_h, Wv_h, Wo_h,
        bq, bk, bv, bo, phase, QR_h, QR_l, KR_h, VT_h, out, 0);
    // 3. attention (QBLK=128)
    k_attn<<<dim3(16, 32), 256, 0, stream>>>(QR_h, QR_l, KR_h, VT_h, AO_h, AO_l);
    // 4. output projection (z=3)
    k_gemm<<<dim3(8, 32, 1), 256, 0, stream>>>(
        q_h, q_l, k_h, k_l, v_h, v_l, AO_h, AO_l,
        Wq_h, Wk_h, Wv_h, Wo_h,
        bq, bk, bv, bo, phase, QR_h, QR_l, KR_h, VT_h, out, 3);
    (void)in_sizes; (void)n_in; (void)out_size; (void)ws_size;
}

// Round 14
// 159.088 us; speedup vs baseline: 1.3813x; 1.1482x over previous
//
#include <hip/hip_runtime.h>
#include <hip/hip_bf16.h>

// PhaseSynchronizedAttention: B=2 S=2048 D=1024 H=16 DK=64, fp32 in/out.
// Round 14: term diet round 2. (1) attn QK^T drops Q-lo (error « P's bf16
// rounding): 52->36 MFMA/tile, QR is hi-only. (2) out-proj is a dedicated
// 1-term kernel k_gemm1 (AOh * Woh); attn epilogue writes AO hi only.
// k_gemm now handles z=0,1,2 only (branch-free per-z as before).

typedef short bf16x8 __attribute__((ext_vector_type(8)));
typedef float f32x4 __attribute__((ext_vector_type(4)));
typedef unsigned short u16;
typedef unsigned short u16x8 __attribute__((ext_vector_type(8)));
typedef unsigned short u16x4 __attribute__((ext_vector_type(4)));

static __device__ __forceinline__ u16 f2bf(float x) {
    __hip_bfloat16 b = __float2bfloat16(x);
    return *reinterpret_cast<u16*>(&b);
}
static __device__ __forceinline__ float bf2f(u16 u) {
    __hip_bfloat16 b = *reinterpret_cast<__hip_bfloat16*>(&u);
    return __bfloat162float(b);
}
static __device__ __forceinline__ void split2(float x, u16& hi, u16& lo) {
    hi = f2bf(x);
    lo = f2bf(x - bf2f(hi));
}
static __device__ __forceinline__ bf16x8 g8(const u16* p) {
    return *reinterpret_cast<const bf16x8*>(p);
}
static __device__ __forceinline__ float fast_exp2(float x) {
#if __has_builtin(__builtin_amdgcn_exp2f)
    return __builtin_amdgcn_exp2f(x);
#else
    return exp2f(x);
#endif
}

// ---------------- merged split: y=0,1,2 -> q,k,v (hi+lo); y=3 -> W's (hi) --
__global__ void k_split(const float* __restrict__ q, const float* __restrict__ k,
                        const float* __restrict__ v,
                        const float* __restrict__ w0, const float* __restrict__ w1,
                        const float* __restrict__ w2, const float* __restrict__ w3,
                        u16* __restrict__ qh, u16* __restrict__ ql,
                        u16* __restrict__ kh, u16* __restrict__ kl,
                        u16* __restrict__ vh, u16* __restrict__ vl,
                        u16* __restrict__ h0, u16* __restrict__ h1,
                        u16* __restrict__ h2, u16* __restrict__ h3) {
    const int i = blockIdx.x * 256 + threadIdx.x;  // grid.x = 4096 -> i < 1048576
    if (blockIdx.y == 3) {
        const int which = i >> 18;
        const int off = i & 262143;
        const float* s = (which == 0) ? w0 : (which == 1) ? w1 : (which == 2) ? w2 : w3;
        u16* H = (which == 0) ? h0 : (which == 1) ? h1 : (which == 2) ? h2 : h3;
        float4 val = reinterpret_cast<const float4*>(s)[off];
        u16x4 h;
        h[0] = f2bf(val.x);
        h[1] = f2bf(val.y);
        h[2] = f2bf(val.z);
        h[3] = f2bf(val.w);
        reinterpret_cast<u16x4*>(H)[off] = h;
        return;
    }
    const float* s;
    u16 *H, *L;
    if (blockIdx.y == 0) { s = q; H = qh; L = ql; }
    else if (blockIdx.y == 1) { s = k; H = kh; L = kl; }
    else { s = v; H = vh; L = vl; }
    float4 val = reinterpret_cast<const float4*>(s)[i];
    u16x4 h, l;
    u16 th, tl2;
    split2(val.x, th, tl2); h[0] = th; l[0] = tl2;
    split2(val.y, th, tl2); h[1] = th; l[1] = tl2;
    split2(val.z, th, tl2); h[2] = th; l[2] = tl2;
    split2(val.w, th, tl2); h[3] = th; l[3] = tl2;
    reinterpret_cast<u16x4*>(H)[i] = h;
    reinterpret_cast<u16x4*>(L)[i] = l;
}

// ---------------- QKV GEMM: C[M,1024] = (Ah+Al) @ Bh^T + bias -------------
// z = blockIdx.z: 0=Q-proj(rotate, scale incl. log2e, hi out), 1=K-proj
// (rotate, hi out), 2=V-proj(fused transpose -> V^T bf16). XCD swizzle.
#define LDP 40  // padded LDS row in elems (80 B)
__global__ __launch_bounds__(256) void k_gemm(
    const u16* __restrict__ qh, const u16* __restrict__ ql,
    const u16* __restrict__ kh, const u16* __restrict__ kl,
    const u16* __restrict__ vh, const u16* __restrict__ vl,
    const u16* __restrict__ Wqh, const u16* __restrict__ Wkh,
    const u16* __restrict__ Wvh,
    const float* __restrict__ bq, const float* __restrict__ bk,
    const float* __restrict__ bv_,
    const float* __restrict__ phase,
    u16* __restrict__ Qrh, u16* __restrict__ Krh,
    u16* __restrict__ VTh) {
    __shared__ __attribute__((aligned(16))) u16 sAh[128 * LDP];
    __shared__ __attribute__((aligned(16))) u16 sAl[128 * LDP];
    __shared__ __attribute__((aligned(16))) u16 sBh[128 * LDP];

    const int z = blockIdx.z;
    const u16 *Ah, *Al, *Bh;
    const float* bias;
    if (z == 0) { Ah = qh; Al = ql; Bh = Wqh; bias = bq; }
    else if (z == 1) { Ah = kh; Al = kl; Bh = Wkh; bias = bk; }
    else { Ah = vh; Al = vl; Bh = Wvh; bias = bv_; }

    const int flat = blockIdx.y * 8 + blockIdx.x;           // 0..255
    const int tau = (flat & 7) * 32 + (flat >> 3);          // bijective
    const int bx = tau & 7, by = tau >> 3;

    const int t = threadIdx.x;
    const int l = t & 63, w = t >> 6;
    const int wr = w >> 1, wc = w & 1;
    const int m0 = by * 128, n0 = bx * 128;

    const int srow = t >> 2;
    const int scol = (t & 3) * 8;
    const u16* pA0h = Ah + (size_t)(m0 + srow) * 1024 + scol;
    const u16* pA1h = Ah + (size_t)(m0 + 64 + srow) * 1024 + scol;
    const u16* pA0l = Al + (size_t)(m0 + srow) * 1024 + scol;
    const u16* pA1l = Al + (size_t)(m0 + 64 + srow) * 1024 + scol;
    const u16* pB0h = Bh + (size_t)(n0 + srow) * 1024 + scol;
    const u16* pB1h = Bh + (size_t)(n0 + 64 + srow) * 1024 + scol;
    const int so0 = srow * LDP + scol;
    const int so1 = (srow + 64) * LDP + scol;

    bf16x8 rA0h, rA1h, rA0l, rA1l, rB0h, rB1h;
    auto load_tiles = [&](int kk) {
        const int ko = kk * 32;
        rA0h = g8(pA0h + ko); rA1h = g8(pA1h + ko);
        rA0l = g8(pA0l + ko); rA1l = g8(pA1l + ko);
        rB0h = g8(pB0h + ko); rB1h = g8(pB1h + ko);
    };

    f32x4 acc[4][4];
#pragma unroll
    for (int m = 0; m < 4; ++m)
#pragma unroll
        for (int n = 0; n < 4; ++n) acc[m][n] = (f32x4){0.f, 0.f, 0.f, 0.f};

    const int fr = l & 15;
    const int fk = (l >> 4) * 8;
    const int ar = wr * 64 + fr;
    const int br = wc * 64 + fr;

    load_tiles(0);
    for (int kk = 0; kk < 32; ++kk) {
        __syncthreads();
        *reinterpret_cast<bf16x8*>(&sAh[so0]) = rA0h;
        *reinterpret_cast<bf16x8*>(&sAh[so1]) = rA1h;
        *reinterpret_cast<bf16x8*>(&sAl[so0]) = rA0l;
        *reinterpret_cast<bf16x8*>(&sAl[so1]) = rA1l;
        *reinterpret_cast<bf16x8*>(&sBh[so0]) = rB0h;
        *reinterpret_cast<bf16x8*>(&sBh[so1]) = rB1h;
        __syncthreads();
        if (kk < 31) load_tiles(kk + 1);

        bf16x8 fa_h[4], fa_l[4], fb_h[4];
#pragma unroll
        for (int m = 0; m < 4; ++m) {
            fa_h[m] = *reinterpret_cast<const bf16x8*>(&sAh[(ar + m * 16) * LDP + fk]);
            fa_l[m] = *reinterpret_cast<const bf16x8*>(&sAl[(ar + m * 16) * LDP + fk]);
        }
#pragma unroll
        for (int n = 0; n < 4; ++n)
            fb_h[n] = *reinterpret_cast<const bf16x8*>(&sBh[(br + n * 16) * LDP + fk]);
#pragma unroll
        for (int m = 0; m < 4; ++m)
#pragma unroll
            for (int n = 0; n < 4; ++n) {
                acc[m][n] = __builtin_amdgcn_mfma_f32_16x16x32_bf16(fa_h[m], fb_h[n], acc[m][n], 0, 0, 0);
                acc[m][n] = __builtin_amdgcn_mfma_f32_16x16x32_bf16(fa_l[m], fb_h[n], acc[m][n], 0, 0, 0);
            }
    }

    const int er4 = (l >> 4) * 4;
    float bvv[4];
#pragma unroll
    for (int n = 0; n < 4; ++n) bvv[n] = bias[n0 + wc * 64 + n * 16 + fr];

    if (z == 2) {
        // fused transpose: V^T[(b*16+h)*64+d][s], 4 consecutive s per thread
#pragma unroll
        for (int m = 0; m < 4; ++m) {
            const int row0 = m0 + wr * 64 + m * 16 + er4;  // s-base (mult of 4)
            const int bb = row0 >> 11;
            const int ss = row0 & 2047;
#pragma unroll
            for (int n = 0; n < 4; ++n) {
                const int col = n0 + wc * 64 + n * 16 + fr;
                const int hh_ = col >> 6, dd = col & 63;
                u16x4 vv;
#pragma unroll
                for (int r = 0; r < 4; ++r) vv[r] = f2bf(acc[m][n][r] + bvv[n]);
                *reinterpret_cast<u16x4*>(
                    &VTh[((size_t)(bb * 16 + hh_) * 64 + dd) * 2048 + ss]) = vv;
            }
        }
    } else {
        // bias + phase rotation + scale + bf16 (hi-only) store.
        u16* Dh = z ? Krh : Qrh;
        const float sc = z ? 1.0f : 0.18033688011112042f;  // (1/8)*log2(e)
        const int head = bx * 2 + wc;
        float sv, cv;
        sincosf(phase[head], &sv, &cv);
#pragma unroll
        for (int m = 0; m < 4; ++m)
#pragma unroll
            for (int n = 0; n < 2; ++n) {
#pragma unroll
                for (int r = 0; r < 4; ++r) {
                    const float xr = acc[m][n][r] + bvv[n];
                    const float xi = acc[m][n + 2][r] + bvv[n + 2];
                    const float o0 = (xr * cv - xi * sv) * sc;
                    const float o1 = (xr * sv + xi * cv) * sc;
                    const int row = m0 + wr * 64 + m * 16 + er4 + r;
                    const size_t i0 = (size_t)row * 1024 + head * 64 + n * 16 + fr;
                    Dh[i0] = f2bf(o0);
                    Dh[i0 + 32] = f2bf(o1);
                }
            }
    }
}

// ---------------- out-proj GEMM (1-term): C = Ah @ Bh^T + bias, fp32 out --
__global__ __launch_bounds__(256) void k_gemm1(
    const u16* __restrict__ Ah, const u16* __restrict__ Bh,
    const float* __restrict__ bias, float* __restrict__ C) {
    __shared__ __attribute__((aligned(16))) u16 sAh[128 * LDP];
    __shared__ __attribute__((aligned(16))) u16 sBh[128 * LDP];

    const int flat = blockIdx.y * 8 + blockIdx.x;           // 0..255
    const int tau = (flat & 7) * 32 + (flat >> 3);          // bijective
    const int bx = tau & 7, by = tau >> 3;

    const int t = threadIdx.x;
    const int l = t & 63, w = t >> 6;
    const int wr = w >> 1, wc = w & 1;
    const int m0 = by * 128, n0 = bx * 128;

    const int srow = t >> 2;
    const int scol = (t & 3) * 8;
    const u16* pA0 = Ah + (size_t)(m0 + srow) * 1024 + scol;
    const u16* pA1 = Ah + (size_t)(m0 + 64 + srow) * 1024 + scol;
    const u16* pB0 = Bh + (size_t)(n0 + srow) * 1024 + scol;
    const u16* pB1 = Bh + (size_t)(n0 + 64 + srow) * 1024 + scol;
    const int so0 = srow * LDP + scol;
    const int so1 = (srow + 64) * LDP + scol;

    bf16x8 rA0, rA1, rB0, rB1;
    auto load_tiles = [&](int kk) {
        const int ko = kk * 32;
        rA0 = g8(pA0 + ko); rA1 = g8(pA1 + ko);
        rB0 = g8(pB0 + ko); rB1 = g8(pB1 + ko);
    };

    f32x4 acc[4][4];
#pragma unroll
    for (int m = 0; m < 4; ++m)
#pragma unroll
        for (int n = 0; n < 4; ++n) acc[m][n] = (f32x4){0.f, 0.f, 0.f, 0.f};

    const int fr = l & 15;
    const int fk = (l >> 4) * 8;
    const int ar = wr * 64 + fr;
    const int br = wc * 64 + fr;

    load_tiles(0);
    for (int kk = 0; kk < 32; ++kk) {
        __syncthreads();
        *reinterpret_cast<bf16x8*>(&sAh[so0]) = rA0;
        *reinterpret_cast<bf16x8*>(&sAh[so1]) = rA1;
        *reinterpret_cast<bf16x8*>(&sBh[so0]) = rB0;
        *reinterpret_cast<bf16x8*>(&sBh[so1]) = rB1;
        __syncthreads();
        if (kk < 31) load_tiles(kk + 1);

        bf16x8 fa[4], fb[4];
#pragma unroll
        for (int m = 0; m < 4; ++m)
            fa[m] = *reinterpret_cast<const bf16x8*>(&sAh[(ar + m * 16) * LDP + fk]);
#pragma unroll
        for (int n = 0; n < 4; ++n)
            fb[n] = *reinterpret_cast<const bf16x8*>(&sBh[(br + n * 16) * LDP + fk]);
#pragma unroll
        for (int m = 0; m < 4; ++m)
#pragma unroll
            for (int n = 0; n < 4; ++n)
                acc[m][n] = __builtin_amdgcn_mfma_f32_16x16x32_bf16(fa[m], fb[n], acc[m][n], 0, 0, 0);
    }

    const int er4 = (l >> 4) * 4;
    float bvv[4];
#pragma unroll
    for (int n = 0; n < 4; ++n) bvv[n] = bias[n0 + wc * 64 + n * 16 + fr];
#pragma unroll
    for (int m = 0; m < 4; ++m)
#pragma unroll
        for (int n = 0; n < 4; ++n) {
            const int col = n0 + wc * 64 + n * 16 + fr;
            const size_t rb = (size_t)(m0 + wr * 64 + m * 16 + er4) * 1024 + col;
#pragma unroll
            for (int r = 0; r < 4; ++r) C[rb + (size_t)r * 1024] = acc[m][n][r] + bvv[n];
        }
}

// ---------------- flash attention (QBLK=128, fixed-max, exp2, dbuf) -------
// grid flat = 512; XCD swizzle tau=(flat&7)*64+flat/8. Wave w owns 32 q-rows
// (2 fragments). QK^T 1-term (Qh only); P = exp2(s - 12*log2e); l via
// ones-MFMA. K/V dbuf XOR-swizzled, 1 barrier/tile. AO hi-only out.
#define SM_M2 17.312340490667562f  // 12 * log2(e)

#define ATTN_TILE(SK, SV)                                                      \
  {                                                                            \
    f32x4 s[2][4];                                                             \
    _Pragma("unroll") for (int qm = 0; qm < 2; ++qm)                           \
      _Pragma("unroll") for (int n = 0; n < 4; ++n)                            \
        s[qm][n] = (f32x4){-SM_M2, -SM_M2, -SM_M2, -SM_M2};                    \
    _Pragma("unroll") for (int n = 0; n < 4; ++n)                              \
      _Pragma("unroll") for (int ks = 0; ks < 2; ++ks) {                       \
        bf16x8 bkh = *reinterpret_cast<const bf16x8*>(                         \
            &SK[(n * 16 + fr) * 64 + ((ks * 32 + fk) ^ rswz)]);                \
        _Pragma("unroll") for (int qm = 0; qm < 2; ++qm)                       \
          s[qm][n] = __builtin_amdgcn_mfma_f32_16x16x32_bf16(aqh[qm][ks], bkh, s[qm][n], 0, 0, 0); \
      }                                                                        \
    _Pragma("unroll") for (int qm = 0; qm < 2; ++qm)                           \
      _Pragma("unroll") for (int n = 0; n < 4; ++n)                            \
        _Pragma("unroll") for (int r = 0; r < 4; ++r) {                        \
          const float p = fast_exp2(s[qm][n][r]);                              \
          const int prow = w * 32 + qm * 16 + (l >> 4) * 4 + r;                \
          const int pcol = (n * 16 + (l & 15)) ^ ((prow & 7) << 3);            \
          sPh[prow * 64 + pcol] = f2bf(p);                                     \
        }                                                                      \
    bf16x8 bph[2][2];                                                          \
    _Pragma("unroll") for (int qm = 0; qm < 2; ++qm)                           \
      _Pragma("unroll") for (int ks = 0; ks < 2; ++ks)                         \
        bph[qm][ks] = *reinterpret_cast<const bf16x8*>(                        \
            &sPh[(w * 32 + qm * 16 + fr) * 64 + ((ks * 32 + fk) ^ rswz)]);     \
    _Pragma("unroll") for (int m = 0; m < 4; ++m)                              \
      _Pragma("unroll") for (int ks = 0; ks < 2; ++ks) {                       \
        bf16x8 avh = *reinterpret_cast<const bf16x8*>(                         \
            &SV[(m * 16 + fr) * 64 + ((ks * 32 + fk) ^ rswz)]);                \
        _Pragma("unroll") for (int qm = 0; qm < 2; ++qm)                       \
          aco[qm][m] = __builtin_amdgcn_mfma_f32_16x16x32_bf16(avh, bph[qm][ks], aco[qm][m], 0, 0, 0); \
      }                                                                        \
    _Pragma("unroll") for (int qm = 0; qm < 2; ++qm)                           \
      _Pragma("unroll") for (int ks = 0; ks < 2; ++ks)                         \
        acl[qm] = __builtin_amdgcn_mfma_f32_16x16x32_bf16(vone, bph[qm][ks], acl[qm], 0, 0, 0); \
  }

#define ATTN_STAGE(SK, SV)                                                     \
  {                                                                            \
    _Pragma("unroll") for (int i = 0; i < 2; ++i) {                            \
      *reinterpret_cast<bf16x8*>(&SK[soff[i]]) = rKh[i];                       \
      *reinterpret_cast<bf16x8*>(&SV[soff[i]]) = rVh[i];                       \
    }                                                                          \
  }

__global__ __launch_bounds__(256) void k_attn(
    const u16* __restrict__ Qh,
    const u16* __restrict__ Kh,
    const u16* __restrict__ VTh,
    u16* __restrict__ AOh) {
    __shared__ __attribute__((aligned(16))) u16 sK0[4096];
    __shared__ __attribute__((aligned(16))) u16 sK1[4096];
    __shared__ __attribute__((aligned(16))) u16 sV0[4096];
    __shared__ __attribute__((aligned(16))) u16 sV1[4096];
    __shared__ __attribute__((aligned(16))) u16 sPh[128 * 64];

    const int t = threadIdx.x;
    const int l = t & 63, w = t >> 6;
    const int flat = blockIdx.y * 16 + blockIdx.x;          // 0..511
    const int tau = (flat & 7) * 64 + (flat >> 3);          // bijective
    const int q0 = (tau & 15) * 128;
    const int bh = tau >> 4;
    const int b = bh >> 4, h = bh & 15;
    const size_t qrow0 = (size_t)b * 2048 + q0;

    const u16* Qb_h = Qh + qrow0 * 1024 + h * 64;
    const u16* Kb_h = Kh + (size_t)b * 2048 * 1024 + h * 64;
    const u16* Vb_h = VTh + (size_t)bh * 64 * 2048;

    const int fr = l & 15;
    const int fk = (l >> 4) * 8;

    bf16x8 aqh[2][2];
#pragma unroll
    for (int qm = 0; qm < 2; ++qm)
#pragma unroll
        for (int ks = 0; ks < 2; ++ks) {
            const size_t qo = (size_t)(w * 32 + qm * 16 + fr) * 1024 + ks * 32 + fk;
            aqh[qm][ks] = g8(Qb_h + qo);
        }

    bf16x8 vone;
#pragma unroll
    for (int j = 0; j < 8; ++j) vone[j] = (short)0x3F80;

    f32x4 aco[2][4];
    f32x4 acl[2];
#pragma unroll
    for (int qm = 0; qm < 2; ++qm) {
        acl[qm] = (f32x4){0.f, 0.f, 0.f, 0.f};
#pragma unroll
        for (int m = 0; m < 4; ++m) aco[qm][m] = (f32x4){0.f, 0.f, 0.f, 0.f};
    }

    const int sr = t >> 3, sc = (t & 7) * 8;  // staging: row sr(+32), col sc
    bf16x8 rKh[2], rVh[2];
    auto load_kv = [&](int tt) {
        const int kv0 = tt * 64;
#pragma unroll
        for (int i = 0; i < 2; ++i) {
            const int r2 = sr + i * 32;
            rKh[i] = g8(Kb_h + (size_t)(kv0 + r2) * 1024 + sc);
            rVh[i] = g8(Vb_h + (size_t)r2 * 2048 + kv0 + sc);
        }
    };
    int soff[2];
#pragma unroll
    for (int i = 0; i < 2; ++i) {
        const int r2 = sr + i * 32;
        soff[i] = r2 * 64 + (sc ^ ((r2 & 7) << 3));
    }
    const int rswz = (fr & 7) << 3;

    // prologue: stage tile 0 into buf0
    load_kv(0);
    ATTN_STAGE(sK0, sV0);
    __syncthreads();

    for (int tt = 0; tt < 32; tt += 2) {
        load_kv(tt + 1);
        ATTN_TILE(sK0, sV0);
        ATTN_STAGE(sK1, sV1);
        __syncthreads();
        if (tt + 2 < 32) load_kv(tt + 2);
        ATTN_TILE(sK1, sV1);
        if (tt + 2 < 32) ATTN_STAGE(sK0, sV0);
        __syncthreads();
    }

#pragma unroll
    for (int qm = 0; qm < 2; ++qm) {
        const float inv = 1.0f / acl[qm][0];
#pragma unroll
        for (int m = 0; m < 4; ++m) aco[qm][m] *= inv;
    }

    // four-pass transpose O^T[d][q] -> O[q][d] via swizzled [32][64] fp32
    // region over sPh; pass p covers q-rows [p*32, p*32+32) = wave p's rows.
    float* Ol = reinterpret_cast<float*>(sPh);
#pragma unroll
    for (int p = 0; p < 4; ++p) {
        __syncthreads();
        if (w == p) {
#pragma unroll
            for (int qm = 0; qm < 2; ++qm) {
                const int qr = qm * 16 + (l & 15);
                const int sw = (qr & 7) << 3;
#pragma unroll
                for (int m = 0; m < 4; ++m)
#pragma unroll
                    for (int r = 0; r < 4; ++r)
                        Ol[qr * 64 + ((m * 16 + (l >> 4) * 4 + r) ^ sw)] = aco[qm][m][r];
            }
        }
        __syncthreads();
        {
            const int qr = t >> 3, cb = (t & 7) * 8;
            const int sw = (qr & 7) << 3;
            const float* srcp = &Ol[qr * 64 + (cb ^ sw)];
            u16x8 oh;
#pragma unroll
            for (int j = 0; j < 8; ++j) oh[j] = f2bf(srcp[j]);
            const size_t ob = (qrow0 + p * 32 + qr) * 1024 + h * 64 + cb;
            *reinterpret_cast<u16x8*>(&AOh[ob]) = oh;
        }
    }
}

// ---------------- host ----------------
extern "C" void kernel_launch(void* const* d_in, const int* in_sizes, int n_in,
                              void* d_out, int out_size, void* d_ws, size_t ws_size,
                              hipStream_t stream) {
    const float* q = (const float*)d_in[0];
    const float* k = (const float*)d_in[1];
    const float* v = (const float*)d_in[2];
    const float* Wq = (const float*)d_in[3];
    const float* bq = (const float*)d_in[4];
    const float* Wk = (const float*)d_in[5];
    const float* bk = (const float*)d_in[6];
    const float* Wv = (const float*)d_in[7];
    const float* bv = (const float*)d_in[8];
    const float* Wo = (const float*)d_in[9];
    const float* bo = (const float*)d_in[10];
    const float* phase = (const float*)d_in[11];
    float* out = (float*)d_out;

    char* ws = (char*)d_ws;
    const size_t MB = 1u << 20;
    u16* Wq_h = (u16*)(ws + 0 * MB);
    u16* Wk_h = (u16*)(ws + 2 * MB);
    u16* Wv_h = (u16*)(ws + 4 * MB);
    u16* Wo_h = (u16*)(ws + 6 * MB);
    u16* q_h = (u16*)(ws + 16 * MB);
    u16* q_l = (u16*)(ws + 24 * MB);
    u16* k_h = (u16*)(ws + 32 * MB);
    u16* k_l = (u16*)(ws + 40 * MB);
    u16* v_h = (u16*)(ws + 48 * MB);
    u16* v_l = (u16*)(ws + 56 * MB);
    u16* QR_h = (u16*)(ws + 64 * MB);
    u16* KR_h = (u16*)(ws + 80 * MB);
    u16* VT_h = (u16*)(ws + 96 * MB);  // z==2 epilogue output; disjoint from
                                        // the v splits its blocks read
    u16* AO_h = (u16*)(ws + 16 * MB);   // over q splits (dead after QKV GEMM)

    // 1. merged splits (one launch)
    k_split<<<dim3(4096, 4), 256, 0, stream>>>(
        q, k, v, Wq, Wk, Wv, Wo,
        q_h, q_l, k_h, k_l, v_h, v_l, Wq_h, Wk_h, Wv_h, Wo_h);
    // 2. fused QKV projections (z=0,1,2); V-proj writes V^T directly
    k_gemm<<<dim3(8, 32, 3), 256, 0, stream>>>(
        q_h, q_l, k_h, k_l, v_h, v_l,
        Wq_h, Wk_h, Wv_h,
        bq, bk, bv, phase, QR_h, KR_h, VT_h);
    // 3. attention (QBLK=128, Q hi-only)
    k_attn<<<dim3(16, 32), 256, 0, stream>>>(QR_h, KR_h, VT_h, AO_h);
    // 4. output projection (1-term)
    k_gemm1<<<dim3(8, 32), 256, 0, stream>>>(AO_h, Wo_h, bo, out);
    (void)in_sizes; (void)n_in; (void)out_size; (void)ws_size;
}

// Round 15
// 136.265 us; speedup vs baseline: 1.6126x; 1.1675x over previous
//
#include <hip/hip_runtime.h>
#include <hip/hip_bf16.h>

// PhaseSynchronizedAttention: B=2 S=2048 D=1024 H=16 DK=64, fp32 in/out.
// Round 15: pure-bf16 pipeline (all projections 1-term hi*hi; input-rounding
// error ~= existing output rounding, averages down through softmax) + GEMM
// LDS [128][32] XOR-swizzle (conflict-free b128 on store AND read; the
// LDP=40 pad was a measured 9.4e6-cycle conflict). Attn frozen from R14.

typedef short bf16x8 __attribute__((ext_vector_type(8)));
typedef float f32x4 __attribute__((ext_vector_type(4)));
typedef unsigned short u16;
typedef unsigned short u16x8 __attribute__((ext_vector_type(8)));
typedef unsigned short u16x4 __attribute__((ext_vector_type(4)));

static __device__ __forceinline__ u16 f2bf(float x) {
    __hip_bfloat16 b = __float2bfloat16(x);
    return *reinterpret_cast<u16*>(&b);
}
static __device__ __forceinline__ bf16x8 g8(const u16* p) {
    return *reinterpret_cast<const bf16x8*>(p);
}
static __device__ __forceinline__ float fast_exp2(float x) {
#if __has_builtin(__builtin_amdgcn_exp2f)
    return __builtin_amdgcn_exp2f(x);
#else
    return exp2f(x);
#endif
}

// swizzled LDS offset for [128][32] u16 tiles: 16B slot s = col/8,
// s' = s ^ ((row>>1)&3) -> bank-group 16*(row&1)+4*s' covers all 32 banks
// across any 16-consecutive-row x 4-slot access -> conflict-free b128.
#define SWZ(row, col) ((row) * 32 + ((col) ^ ((((row) >> 1) & 3) << 3)))

// ---------------- merged split: all hi-only (q,k,v,W) ----------------
__global__ void k_split(const float* __restrict__ q, const float* __restrict__ k,
                        const float* __restrict__ v,
                        const float* __restrict__ w0, const float* __restrict__ w1,
                        const float* __restrict__ w2, const float* __restrict__ w3,
                        u16* __restrict__ qh, u16* __restrict__ kh,
                        u16* __restrict__ vh,
                        u16* __restrict__ h0, u16* __restrict__ h1,
                        u16* __restrict__ h2, u16* __restrict__ h3) {
    const int i = blockIdx.x * 256 + threadIdx.x;  // grid.x = 4096 -> i < 1048576
    const float* s;
    u16* H;
    if (blockIdx.y == 3) {
        const int which = i >> 18;
        const int off = i & 262143;
        s = (which == 0) ? w0 : (which == 1) ? w1 : (which == 2) ? w2 : w3;
        H = (which == 0) ? h0 : (which == 1) ? h1 : (which == 2) ? h2 : h3;
        float4 val = reinterpret_cast<const float4*>(s)[off];
        u16x4 h;
        h[0] = f2bf(val.x); h[1] = f2bf(val.y);
        h[2] = f2bf(val.z); h[3] = f2bf(val.w);
        reinterpret_cast<u16x4*>(H)[off] = h;
        return;
    }
    if (blockIdx.y == 0) { s = q; H = qh; }
    else if (blockIdx.y == 1) { s = k; H = kh; }
    else { s = v; H = vh; }
    float4 val = reinterpret_cast<const float4*>(s)[i];
    u16x4 h;
    h[0] = f2bf(val.x); h[1] = f2bf(val.y);
    h[2] = f2bf(val.z); h[3] = f2bf(val.w);
    reinterpret_cast<u16x4*>(H)[i] = h;
}

// ---------------- QKV GEMM (1-term): C = Ah @ Bh^T + bias -----------------
// z = blockIdx.z: 0=Q-proj(rotate, scale incl. log2e, hi out), 1=K-proj
// (rotate, hi out), 2=V-proj(fused transpose -> V^T bf16). XCD swizzle.
__global__ __launch_bounds__(256) void k_gemm(
    const u16* __restrict__ qh, const u16* __restrict__ kh,
    const u16* __restrict__ vh,
    const u16* __restrict__ Wqh, const u16* __restrict__ Wkh,
    const u16* __restrict__ Wvh,
    const float* __restrict__ bq, const float* __restrict__ bk,
    const float* __restrict__ bv_,
    const float* __restrict__ phase,
    u16* __restrict__ Qrh, u16* __restrict__ Krh,
    u16* __restrict__ VTh) {
    __shared__ __attribute__((aligned(16))) u16 sA[128 * 32];
    __shared__ __attribute__((aligned(16))) u16 sB[128 * 32];

    const int z = blockIdx.z;
    const u16 *Ah, *Bh;
    const float* bias;
    if (z == 0) { Ah = qh; Bh = Wqh; bias = bq; }
    else if (z == 1) { Ah = kh; Bh = Wkh; bias = bk; }
    else { Ah = vh; Bh = Wvh; bias = bv_; }

    const int flat = blockIdx.y * 8 + blockIdx.x;           // 0..255
    const int tau = (flat & 7) * 32 + (flat >> 3);          // bijective
    const int bx = tau & 7, by = tau >> 3;

    const int t = threadIdx.x;
    const int l = t & 63, w = t >> 6;
    const int wr = w >> 1, wc = w & 1;
    const int m0 = by * 128, n0 = bx * 128;

    const int srow = t >> 2;
    const int scol = (t & 3) * 8;
    const u16* pA0 = Ah + (size_t)(m0 + srow) * 1024 + scol;
    const u16* pA1 = Ah + (size_t)(m0 + 64 + srow) * 1024 + scol;
    const u16* pB0 = Bh + (size_t)(n0 + srow) * 1024 + scol;
    const u16* pB1 = Bh + (size_t)(n0 + 64 + srow) * 1024 + scol;
    const int so0 = SWZ(srow, scol);
    const int so1 = SWZ(srow + 64, scol);

    bf16x8 rA0, rA1, rB0, rB1;
    auto load_tiles = [&](int kk) {
        const int ko = kk * 32;
        rA0 = g8(pA0 + ko); rA1 = g8(pA1 + ko);
        rB0 = g8(pB0 + ko); rB1 = g8(pB1 + ko);
    };

    f32x4 acc[4][4];
#pragma unroll
    for (int m = 0; m < 4; ++m)
#pragma unroll
        for (int n = 0; n < 4; ++n) acc[m][n] = (f32x4){0.f, 0.f, 0.f, 0.f};

    const int fr = l & 15;
    const int fk = (l >> 4) * 8;
    const int ar = wr * 64 + fr;
    const int br = wc * 64 + fr;

    load_tiles(0);
    for (int kk = 0; kk < 32; ++kk) {
        __syncthreads();
        *reinterpret_cast<bf16x8*>(&sA[so0]) = rA0;
        *reinterpret_cast<bf16x8*>(&sA[so1]) = rA1;
        *reinterpret_cast<bf16x8*>(&sB[so0]) = rB0;
        *reinterpret_cast<bf16x8*>(&sB[so1]) = rB1;
        __syncthreads();
        if (kk < 31) load_tiles(kk + 1);

        bf16x8 fa[4], fb[4];
#pragma unroll
        for (int m = 0; m < 4; ++m)
            fa[m] = *reinterpret_cast<const bf16x8*>(&sA[SWZ(ar + m * 16, fk)]);
#pragma unroll
        for (int n = 0; n < 4; ++n)
            fb[n] = *reinterpret_cast<const bf16x8*>(&sB[SWZ(br + n * 16, fk)]);
#pragma unroll
        for (int m = 0; m < 4; ++m)
#pragma unroll
            for (int n = 0; n < 4; ++n)
                acc[m][n] = __builtin_amdgcn_mfma_f32_16x16x32_bf16(fa[m], fb[n], acc[m][n], 0, 0, 0);
    }

    const int er4 = (l >> 4) * 4;
    float bvv[4];
#pragma unroll
    for (int n = 0; n < 4; ++n) bvv[n] = bias[n0 + wc * 64 + n * 16 + fr];

    if (z == 2) {
        // fused transpose: V^T[(b*16+h)*64+d][s], 4 consecutive s per thread
#pragma unroll
        for (int m = 0; m < 4; ++m) {
            const int row0 = m0 + wr * 64 + m * 16 + er4;  // s-base (mult of 4)
            const int bb = row0 >> 11;
            const int ss = row0 & 2047;
#pragma unroll
            for (int n = 0; n < 4; ++n) {
                const int col = n0 + wc * 64 + n * 16 + fr;
                const int hh_ = col >> 6, dd = col & 63;
                u16x4 vv;
#pragma unroll
                for (int r = 0; r < 4; ++r) vv[r] = f2bf(acc[m][n][r] + bvv[n]);
                *reinterpret_cast<u16x4*>(
                    &VTh[((size_t)(bb * 16 + hh_) * 64 + dd) * 2048 + ss]) = vv;
            }
        }
    } else {
        // bias + phase rotation + scale + bf16 (hi-only) store.
        u16* Dh = z ? Krh : Qrh;
        const float sc = z ? 1.0f : 0.18033688011112042f;  // (1/8)*log2(e)
        const int head = bx * 2 + wc;
        float sv, cv;
        sincosf(phase[head], &sv, &cv);
#pragma unroll
        for (int m = 0; m < 4; ++m)
#pragma unroll
            for (int n = 0; n < 2; ++n) {
#pragma unroll
                for (int r = 0; r < 4; ++r) {
                    const float xr = acc[m][n][r] + bvv[n];
                    const float xi = acc[m][n + 2][r] + bvv[n + 2];
                    const float o0 = (xr * cv - xi * sv) * sc;
                    const float o1 = (xr * sv + xi * cv) * sc;
                    const int row = m0 + wr * 64 + m * 16 + er4 + r;
                    const size_t i0 = (size_t)row * 1024 + head * 64 + n * 16 + fr;
                    Dh[i0] = f2bf(o0);
                    Dh[i0 + 32] = f2bf(o1);
                }
            }
    }
}

// ---------------- out-proj GEMM (1-term): C = Ah @ Bh^T + bias, fp32 out --
__global__ __launch_bounds__(256) void k_gemm1(
    const u16* __restrict__ Ah, const u16* __restrict__ Bh,
    const float* __restrict__ bias, float* __restrict__ C) {
    __shared__ __attribute__((aligned(16))) u16 sA[128 * 32];
    __shared__ __attribute__((aligned(16))) u16 sB[128 * 32];

    const int flat = blockIdx.y * 8 + blockIdx.x;           // 0..255
    const int tau = (flat & 7) * 32 + (flat >> 3);          // bijective
    const int bx = tau & 7, by = tau >> 3;

    const int t = threadIdx.x;
    const int l = t & 63, w = t >> 6;
    const int wr = w >> 1, wc = w & 1;
    const int m0 = by * 128, n0 = bx * 128;

    const int srow = t >> 2;
    const int scol = (t & 3) * 8;
    const u16* pA0 = Ah + (size_t)(m0 + srow) * 1024 + scol;
    const u16* pA1 = Ah + (size_t)(m0 + 64 + srow) * 1024 + scol;
    const u16* pB0 = Bh + (size_t)(n0 + srow) * 1024 + scol;
    const u16* pB1 = Bh + (size_t)(n0 + 64 + srow) * 1024 + scol;
    const int so0 = SWZ(srow, scol);
    const int so1 = SWZ(srow + 64, scol);

    bf16x8 rA0, rA1, rB0, rB1;
    auto load_tiles = [&](int kk) {
        const int ko = kk * 32;
        rA0 = g8(pA0 + ko); rA1 = g8(pA1 + ko);
        rB0 = g8(pB0 + ko); rB1 = g8(pB1 + ko);
    };

    f32x4 acc[4][4];
#pragma unroll
    for (int m = 0; m < 4; ++m)
#pragma unroll
        for (int n = 0; n < 4; ++n) acc[m][n] = (f32x4){0.f, 0.f, 0.f, 0.f};

    const int fr = l & 15;
    const int fk = (l >> 4) * 8;
    const int ar = wr * 64 + fr;
    const int br = wc * 64 + fr;

    load_tiles(0);
    for (int kk = 0; kk < 32; ++kk) {
        __syncthreads();
        *reinterpret_cast<bf16x8*>(&sA[so0]) = rA0;
        *reinterpret_cast<bf16x8*>(&sA[so1]) = rA1;
        *reinterpret_cast<bf16x8*>(&sB[so0]) = rB0;
        *reinterpret_cast<bf16x8*>(&sB[so1]) = rB1;
        __syncthreads();
        if (kk < 31) load_tiles(kk + 1);

        bf16x8 fa[4], fb[4];
#pragma unroll
        for (int m = 0; m < 4; ++m)
            fa[m] = *reinterpret_cast<const bf16x8*>(&sA[SWZ(ar + m * 16, fk)]);
#pragma unroll
        for (int n = 0; n < 4; ++n)
            fb[n] = *reinterpret_cast<const bf16x8*>(&sB[SWZ(br + n * 16, fk)]);
#pragma unroll
        for (int m = 0; m < 4; ++m)
#pragma unroll
            for (int n = 0; n < 4; ++n)
                acc[m][n] = __builtin_amdgcn_mfma_f32_16x16x32_bf16(fa[m], fb[n], acc[m][n], 0, 0, 0);
    }

    const int er4 = (l >> 4) * 4;
    float bvv[4];
#pragma unroll
    for (int n = 0; n < 4; ++n) bvv[n] = bias[n0 + wc * 64 + n * 16 + fr];
#pragma unroll
    for (int m = 0; m < 4; ++m)
#pragma unroll
        for (int n = 0; n < 4; ++n) {
            const int col = n0 + wc * 64 + n * 16 + fr;
            const size_t rb = (size_t)(m0 + wr * 64 + m * 16 + er4) * 1024 + col;
#pragma unroll
            for (int r = 0; r < 4; ++r) C[rb + (size_t)r * 1024] = acc[m][n][r] + bvv[n];
        }
}

// ---------------- flash attention (QBLK=128, fixed-max, exp2, dbuf) -------
// grid flat = 512; XCD swizzle tau=(flat&7)*64+flat/8. Wave w owns 32 q-rows
// (2 fragments). QK^T 1-term; P = exp2(s - 12*log2e); l via ones-MFMA.
// K/V dbuf XOR-swizzled, 1 barrier/tile. AO hi-only out. (frozen from R14)
#define SM_M2 17.312340490667562f  // 12 * log2(e)

#define ATTN_TILE(SK, SV)                                                      \
  {                                                                            \
    f32x4 s[2][4];                                                             \
    _Pragma("unroll") for (int qm = 0; qm < 2; ++qm)                           \
      _Pragma("unroll") for (int n = 0; n < 4; ++n)                            \
        s[qm][n] = (f32x4){-SM_M2, -SM_M2, -SM_M2, -SM_M2};                    \
    _Pragma("unroll") for (int n = 0; n < 4; ++n)                              \
      _Pragma("unroll") for (int ks = 0; ks < 2; ++ks) {                       \
        bf16x8 bkh = *reinterpret_cast<const bf16x8*>(                         \
            &SK[(n * 16 + fr) * 64 + ((ks * 32 + fk) ^ rswz)]);                \
        _Pragma("unroll") for (int qm = 0; qm < 2; ++qm)                       \
          s[qm][n] = __builtin_amdgcn_mfma_f32_16x16x32_bf16(aqh[qm][ks], bkh, s[qm][n], 0, 0, 0); \
      }                                                                        \
    _Pragma("unroll") for (int qm = 0; qm < 2; ++qm)                           \
      _Pragma("unroll") for (int n = 0; n < 4; ++n)                            \
        _Pragma("unroll") for (int r = 0; r < 4; ++r) {                        \
          const float p = fast_exp2(s[qm][n][r]);                              \
          const int prow = w * 32 + qm * 16 + (l >> 4) * 4 + r;                \
          const int pcol = (n * 16 + (l & 15)) ^ ((prow & 7) << 3);            \
          sPh[prow * 64 + pcol] = f2bf(p);                                     \
        }                                                                      \
    bf16x8 bph[2][2];                                                          \
    _Pragma("unroll") for (int qm = 0; qm < 2; ++qm)                           \
      _Pragma("unroll") for (int ks = 0; ks < 2; ++ks)                         \
        bph[qm][ks] = *reinterpret_cast<const bf16x8*>(                        \
            &sPh[(w * 32 + qm * 16 + fr) * 64 + ((ks * 32 + fk) ^ rswz)]);     \
    _Pragma("unroll") for (int m = 0; m < 4; ++m)                              \
      _Pragma("unroll") for (int ks = 0; ks < 2; ++ks) {                       \
        bf16x8 avh = *reinterpret_cast<const bf16x8*>(                         \
            &SV[(m * 16 + fr) * 64 + ((ks * 32 + fk) ^ rswz)]);                \
        _Pragma("unroll") for (int qm = 0; qm < 2; ++qm)                       \
          aco[qm][m] = __builtin_amdgcn_mfma_f32_16x16x32_bf16(avh, bph[qm][ks], aco[qm][m], 0, 0, 0); \
      }                                                                        \
    _Pragma("unroll") for (int qm = 0; qm < 2; ++qm)                           \
      _Pragma("unroll") for (int ks = 0; ks < 2; ++ks)                         \
        acl[qm] = __builtin_amdgcn_mfma_f32_16x16x32_bf16(vone, bph[qm][ks], acl[qm], 0, 0, 0); \
  }

#define ATTN_STAGE(SK, SV)                                                     \
  {                                                                            \
    _Pragma("unroll") for (int i = 0; i < 2; ++i) {                            \
      *reinterpret_cast<bf16x8*>(&SK[soff[i]]) = rKh[i];                       \
      *reinterpret_cast<bf16x8*>(&SV[soff[i]]) = rVh[i];                       \
    }                                                                          \
  }

__global__ __launch_bounds__(256) void k_attn(
    const u16* __restrict__ Qh,
    const u16* __restrict__ Kh,
    const u16* __restrict__ VTh,
    u16* __restrict__ AOh) {
    __shared__ __attribute__((aligned(16))) u16 sK0[4096];
    __shared__ __attribute__((aligned(16))) u16 sK1[4096];
    __shared__ __attribute__((aligned(16))) u16 sV0[4096];
    __shared__ __attribute__((aligned(16))) u16 sV1[4096];
    __shared__ __attribute__((aligned(16))) u16 sPh[128 * 64];

    const int t = threadIdx.x;
    const int l = t & 63, w = t >> 6;
    const int flat = blockIdx.y * 16 + blockIdx.x;          // 0..511
    const int tau = (flat & 7) * 64 + (flat >> 3);          // bijective
    const int q0 = (tau & 15) * 128;
    const int bh = tau >> 4;
    const int b = bh >> 4, h = bh & 15;
    const size_t qrow0 = (size_t)b * 2048 + q0;

    const u16* Qb_h = Qh + qrow0 * 1024 + h * 64;
    const u16* Kb_h = Kh + (size_t)b * 2048 * 1024 + h * 64;
    const u16* Vb_h = VTh + (size_t)bh * 64 * 2048;

    const int fr = l & 15;
    const int fk = (l >> 4) * 8;

    bf16x8 aqh[2][2];
#pragma unroll
    for (int qm = 0; qm < 2; ++qm)
#pragma unroll
        for (int ks = 0; ks < 2; ++ks) {
            const size_t qo = (size_t)(w * 32 + qm * 16 + fr) * 1024 + ks * 32 + fk;
            aqh[qm][ks] = g8(Qb_h + qo);
        }

    bf16x8 vone;
#pragma unroll
    for (int j = 0; j < 8; ++j) vone[j] = (short)0x3F80;

    f32x4 aco[2][4];
    f32x4 acl[2];
#pragma unroll
    for (int qm = 0; qm < 2; ++qm) {
        acl[qm] = (f32x4){0.f, 0.f, 0.f, 0.f};
#pragma unroll
        for (int m = 0; m < 4; ++m) aco[qm][m] = (f32x4){0.f, 0.f, 0.f, 0.f};
    }

    const int sr = t >> 3, sc = (t & 7) * 8;  // staging: row sr(+32), col sc
    bf16x8 rKh[2], rVh[2];
    auto load_kv = [&](int tt) {
        const int kv0 = tt * 64;
#pragma unroll
        for (int i = 0; i < 2; ++i) {
            const int r2 = sr + i * 32;
            rKh[i] = g8(Kb_h + (size_t)(kv0 + r2) * 1024 + sc);
            rVh[i] = g8(Vb_h + (size_t)r2 * 2048 + kv0 + sc);
        }
    };
    int soff[2];
#pragma unroll
    for (int i = 0; i < 2; ++i) {
        const int r2 = sr + i * 32;
        soff[i] = r2 * 64 + (sc ^ ((r2 & 7) << 3));
    }
    const int rswz = (fr & 7) << 3;

    // prologue: stage tile 0 into buf0
    load_kv(0);
    ATTN_STAGE(sK0, sV0);
    __syncthreads();

    for (int tt = 0; tt < 32; tt += 2) {
        load_kv(tt + 1);
        ATTN_TILE(sK0, sV0);
        ATTN_STAGE(sK1, sV1);
        __syncthreads();
        if (tt + 2 < 32) load_kv(tt + 2);
        ATTN_TILE(sK1, sV1);
        if (tt + 2 < 32) ATTN_STAGE(sK0, sV0);
        __syncthreads();
    }

#pragma unroll
    for (int qm = 0; qm < 2; ++qm) {
        const float inv = 1.0f / acl[qm][0];
#pragma unroll
        for (int m = 0; m < 4; ++m) aco[qm][m] *= inv;
    }

    // four-pass transpose O^T[d][q] -> O[q][d] via swizzled [32][64] fp32
    // region over sPh; pass p covers q-rows [p*32, p*32+32) = wave p's rows.
    float* Ol = reinterpret_cast<float*>(sPh);
#pragma unroll
    for (int p = 0; p < 4; ++p) {
        __syncthreads();
        if (w == p) {
#pragma unroll
            for (int qm = 0; qm < 2; ++qm) {
                const int qr = qm * 16 + (l & 15);
                const int sw = (qr & 7) << 3;
#pragma unroll
                for (int m = 0; m < 4; ++m)
#pragma unroll
                    for (int r = 0; r < 4; ++r)
                        Ol[qr * 64 + ((m * 16 + (l >> 4) * 4 + r) ^ sw)] = aco[qm][m][r];
            }
        }
        __syncthreads();
        {
            const int qr = t >> 3, cb = (t & 7) * 8;
            const int sw = (qr & 7) << 3;
            const float* srcp = &Ol[qr * 64 + (cb ^ sw)];
            u16x8 oh;
#pragma unroll
            for (int j = 0; j < 8; ++j) oh[j] = f2bf(srcp[j]);
            const size_t ob = (qrow0 + p * 32 + qr) * 1024 + h * 64 + cb;
            *reinterpret_cast<u16x8*>(&AOh[ob]) = oh;
        }
    }
}

// ---------------- host ----------------
extern "C" void kernel_launch(void* const* d_in, const int* in_sizes, int n_in,
                              void* d_out, int out_size, void* d_ws, size_t ws_size,
                              hipStream_t stream) {
    const float* q = (const float*)d_in[0];
    const float* k = (const float*)d_in[1];
    const float* v = (const float*)d_in[2];
    const float* Wq = (const float*)d_in[3];
    const float* bq = (const float*)d_in[4];
    const float* Wk = (const float*)d_in[5];
    const float* bk = (const float*)d_in[6];
    const float* Wv = (const float*)d_in[7];
    const float* bv = (const float*)d_in[8];
    const float* Wo = (const float*)d_in[9];
    const float* bo = (const float*)d_in[10];
    const float* phase = (const float*)d_in[11];
    float* out = (float*)d_out;

    char* ws = (char*)d_ws;
    const size_t MB = 1u << 20;
    u16* Wq_h = (u16*)(ws + 0 * MB);
    u16* Wk_h = (u16*)(ws + 2 * MB);
    u16* Wv_h = (u16*)(ws + 4 * MB);
    u16* Wo_h = (u16*)(ws + 6 * MB);
    u16* q_h = (u16*)(ws + 16 * MB);
    u16* k_h = (u16*)(ws + 24 * MB);
    u16* v_h = (u16*)(ws + 32 * MB);
    u16* QR_h = (u16*)(ws + 64 * MB);
    u16* KR_h = (u16*)(ws + 80 * MB);
    u16* VT_h = (u16*)(ws + 96 * MB);  // z==2 epilogue output; disjoint from
                                        // the v split its blocks read
    u16* AO_h = (u16*)(ws + 16 * MB);   // over q_h (dead after QKV GEMM)

    // 1. merged splits (one launch, hi-only)
    k_split<<<dim3(4096, 4), 256, 0, stream>>>(
        q, k, v, Wq, Wk, Wv, Wo,
        q_h, k_h, v_h, Wq_h, Wk_h, Wv_h, Wo_h);
    // 2. fused QKV projections (z=0,1,2); V-proj writes V^T directly
    k_gemm<<<dim3(8, 32, 3), 256, 0, stream>>>(
        q_h, k_h, v_h, Wq_h, Wk_h, Wv_h,
        bq, bk, bv, phase, QR_h, KR_h, VT_h);
    // 3. attention (QBLK=128)
    k_attn<<<dim3(16, 32), 256, 0, stream>>>(QR_h, KR_h, VT_h, AO_h);
    // 4. output projection (1-term)
    k_gemm1<<<dim3(8, 32), 256, 0, stream>>>(AO_h, Wo_h, bo, out);
    (void)in_sizes; (void)n_in; (void)out_size; (void)ws_size;
}

// Round 16
// 128.092 us; speedup vs baseline: 1.7155x; 1.0638x over previous
//
#include <hip/hip_runtime.h>
#include <hip/hip_bf16.h>

// PhaseSynchronizedAttention: B=2 S=2048 D=1024 H=16 DK=64, fp32 in/out.
// Round 16: (1) delete the q/k/v split kernel — k_gemm stages A directly
// from fp32 with in-reg cvt (bit-identical rounding); W keeps a small
// pre-split (L2 pressure). (2) k_attn epilogue: wave-private O-transpose
// through dead per-wave K/V LDS buffers (8 barriers -> 1). Core loops frozen.

typedef short bf16x8 __attribute__((ext_vector_type(8)));
typedef float f32x4 __attribute__((ext_vector_type(4)));
typedef unsigned short u16;
typedef unsigned short u16x8 __attribute__((ext_vector_type(8)));
typedef unsigned short u16x4 __attribute__((ext_vector_type(4)));

static __device__ __forceinline__ u16 f2bf(float x) {
    __hip_bfloat16 b = __float2bfloat16(x);
    return *reinterpret_cast<u16*>(&b);
}
static __device__ __forceinline__ bf16x8 g8(const u16* p) {
    return *reinterpret_cast<const bf16x8*>(p);
}
static __device__ __forceinline__ float fast_exp2(float x) {
#if __has_builtin(__builtin_amdgcn_exp2f)
    return __builtin_amdgcn_exp2f(x);
#else
    return exp2f(x);
#endif
}
static __device__ __forceinline__ u16x8 cvt8(const float4& a, const float4& b) {
    u16x8 r;
    r[0] = f2bf(a.x); r[1] = f2bf(a.y); r[2] = f2bf(a.z); r[3] = f2bf(a.w);
    r[4] = f2bf(b.x); r[5] = f2bf(b.y); r[6] = f2bf(b.z); r[7] = f2bf(b.w);
    return r;
}

// swizzled LDS offset for [128][32] u16 tiles (conflict-free b128).
#define SWZ(row, col) ((row) * 32 + ((col) ^ ((((row) >> 1) & 3) << 3)))

// ---------------- weight split (hi-only): grid (1024, 4) ----------------
__global__ void k_splitW(const float* __restrict__ w0, const float* __restrict__ w1,
                         const float* __restrict__ w2, const float* __restrict__ w3,
                         u16* __restrict__ h0, u16* __restrict__ h1,
                         u16* __restrict__ h2, u16* __restrict__ h3) {
    const int i = blockIdx.x * 256 + threadIdx.x;  // < 262144 float4s
    const float* s;
    u16* H;
    if (blockIdx.y == 0) { s = w0; H = h0; }
    else if (blockIdx.y == 1) { s = w1; H = h1; }
    else if (blockIdx.y == 2) { s = w2; H = h2; }
    else { s = w3; H = h3; }
    float4 val = reinterpret_cast<const float4*>(s)[i];
    u16x4 h;
    h[0] = f2bf(val.x); h[1] = f2bf(val.y);
    h[2] = f2bf(val.z); h[3] = f2bf(val.w);
    reinterpret_cast<u16x4*>(H)[i] = h;
}

// ---------------- QKV GEMM (1-term, fp32-A fused cvt) ---------------------
// z = blockIdx.z: 0=Q-proj(rotate, scale incl. log2e, hi out), 1=K-proj
// (rotate, hi out), 2=V-proj(fused transpose -> V^T bf16). XCD swizzle.
__global__ __launch_bounds__(256) void k_gemm(
    const float* __restrict__ qf, const float* __restrict__ kf,
    const float* __restrict__ vf,
    const u16* __restrict__ Wqh, const u16* __restrict__ Wkh,
    const u16* __restrict__ Wvh,
    const float* __restrict__ bq, const float* __restrict__ bk,
    const float* __restrict__ bv_,
    const float* __restrict__ phase,
    u16* __restrict__ Qrh, u16* __restrict__ Krh,
    u16* __restrict__ VTh) {
    __shared__ __attribute__((aligned(16))) u16 sA[128 * 32];
    __shared__ __attribute__((aligned(16))) u16 sB[128 * 32];

    const int z = blockIdx.z;
    const float* Af;
    const u16* Bh;
    const float* bias;
    if (z == 0) { Af = qf; Bh = Wqh; bias = bq; }
    else if (z == 1) { Af = kf; Bh = Wkh; bias = bk; }
    else { Af = vf; Bh = Wvh; bias = bv_; }

    const int flat = blockIdx.y * 8 + blockIdx.x;           // 0..255
    const int tau = (flat & 7) * 32 + (flat >> 3);          // bijective
    const int bx = tau & 7, by = tau >> 3;

    const int t = threadIdx.x;
    const int l = t & 63, w = t >> 6;
    const int wr = w >> 1, wc = w & 1;
    const int m0 = by * 128, n0 = bx * 128;

    const int srow = t >> 2;
    const int scol = (t & 3) * 8;
    const float* pA0 = Af + (size_t)(m0 + srow) * 1024 + scol;
    const float* pA1 = Af + (size_t)(m0 + 64 + srow) * 1024 + scol;
    const u16* pB0 = Bh + (size_t)(n0 + srow) * 1024 + scol;
    const u16* pB1 = Bh + (size_t)(n0 + 64 + srow) * 1024 + scol;
    const int so0 = SWZ(srow, scol);
    const int so1 = SWZ(srow + 64, scol);

    u16x8 rA0, rA1;
    bf16x8 rB0, rB1;
    auto load_tiles = [&](int kk) {
        const int ko = kk * 32;
        float4 a00 = *reinterpret_cast<const float4*>(pA0 + ko);
        float4 a01 = *reinterpret_cast<const float4*>(pA0 + ko + 4);
        float4 a10 = *reinterpret_cast<const float4*>(pA1 + ko);
        float4 a11 = *reinterpret_cast<const float4*>(pA1 + ko + 4);
        rB0 = g8(pB0 + ko);
        rB1 = g8(pB1 + ko);
        rA0 = cvt8(a00, a01);
        rA1 = cvt8(a10, a11);
    };

    f32x4 acc[4][4];
#pragma unroll
    for (int m = 0; m < 4; ++m)
#pragma unroll
        for (int n = 0; n < 4; ++n) acc[m][n] = (f32x4){0.f, 0.f, 0.f, 0.f};

    const int fr = l & 15;
    const int fk = (l >> 4) * 8;
    const int ar = wr * 64 + fr;
    const int br = wc * 64 + fr;

    load_tiles(0);
    for (int kk = 0; kk < 32; ++kk) {
        __syncthreads();
        *reinterpret_cast<u16x8*>(&sA[so0]) = rA0;
        *reinterpret_cast<u16x8*>(&sA[so1]) = rA1;
        *reinterpret_cast<bf16x8*>(&sB[so0]) = rB0;
        *reinterpret_cast<bf16x8*>(&sB[so1]) = rB1;
        __syncthreads();
        if (kk < 31) load_tiles(kk + 1);

        bf16x8 fa[4], fb[4];
#pragma unroll
        for (int m = 0; m < 4; ++m)
            fa[m] = *reinterpret_cast<const bf16x8*>(&sA[SWZ(ar + m * 16, fk)]);
#pragma unroll
        for (int n = 0; n < 4; ++n)
            fb[n] = *reinterpret_cast<const bf16x8*>(&sB[SWZ(br + n * 16, fk)]);
#pragma unroll
        for (int m = 0; m < 4; ++m)
#pragma unroll
            for (int n = 0; n < 4; ++n)
                acc[m][n] = __builtin_amdgcn_mfma_f32_16x16x32_bf16(fa[m], fb[n], acc[m][n], 0, 0, 0);
    }

    const int er4 = (l >> 4) * 4;
    float bvv[4];
#pragma unroll
    for (int n = 0; n < 4; ++n) bvv[n] = bias[n0 + wc * 64 + n * 16 + fr];

    if (z == 2) {
        // fused transpose: V^T[(b*16+h)*64+d][s], 4 consecutive s per thread
#pragma unroll
        for (int m = 0; m < 4; ++m) {
            const int row0 = m0 + wr * 64 + m * 16 + er4;  // s-base (mult of 4)
            const int bb = row0 >> 11;
            const int ss = row0 & 2047;
#pragma unroll
            for (int n = 0; n < 4; ++n) {
                const int col = n0 + wc * 64 + n * 16 + fr;
                const int hh_ = col >> 6, dd = col & 63;
                u16x4 vv;
#pragma unroll
                for (int r = 0; r < 4; ++r) vv[r] = f2bf(acc[m][n][r] + bvv[n]);
                *reinterpret_cast<u16x4*>(
                    &VTh[((size_t)(bb * 16 + hh_) * 64 + dd) * 2048 + ss]) = vv;
            }
        }
    } else {
        // bias + phase rotation + scale + bf16 (hi-only) store.
        u16* Dh = z ? Krh : Qrh;
        const float sc = z ? 1.0f : 0.18033688011112042f;  // (1/8)*log2(e)
        const int head = bx * 2 + wc;
        float sv, cv;
        sincosf(phase[head], &sv, &cv);
#pragma unroll
        for (int m = 0; m < 4; ++m)
#pragma unroll
            for (int n = 0; n < 2; ++n) {
#pragma unroll
                for (int r = 0; r < 4; ++r) {
                    const float xr = acc[m][n][r] + bvv[n];
                    const float xi = acc[m][n + 2][r] + bvv[n + 2];
                    const float o0 = (xr * cv - xi * sv) * sc;
                    const float o1 = (xr * sv + xi * cv) * sc;
                    const int row = m0 + wr * 64 + m * 16 + er4 + r;
                    const size_t i0 = (size_t)row * 1024 + head * 64 + n * 16 + fr;
                    Dh[i0] = f2bf(o0);
                    Dh[i0 + 32] = f2bf(o1);
                }
            }
    }
}

// ---------------- out-proj GEMM (1-term): C = Ah @ Bh^T + bias, fp32 out --
__global__ __launch_bounds__(256) void k_gemm1(
    const u16* __restrict__ Ah, const u16* __restrict__ Bh,
    const float* __restrict__ bias, float* __restrict__ C) {
    __shared__ __attribute__((aligned(16))) u16 sA[128 * 32];
    __shared__ __attribute__((aligned(16))) u16 sB[128 * 32];

    const int flat = blockIdx.y * 8 + blockIdx.x;           // 0..255
    const int tau = (flat & 7) * 32 + (flat >> 3);          // bijective
    const int bx = tau & 7, by = tau >> 3;

    const int t = threadIdx.x;
    const int l = t & 63, w = t >> 6;
    const int wr = w >> 1, wc = w & 1;
    const int m0 = by * 128, n0 = bx * 128;

    const int srow = t >> 2;
    const int scol = (t & 3) * 8;
    const u16* pA0 = Ah + (size_t)(m0 + srow) * 1024 + scol;
    const u16* pA1 = Ah + (size_t)(m0 + 64 + srow) * 1024 + scol;
    const u16* pB0 = Bh + (size_t)(n0 + srow) * 1024 + scol;
    const u16* pB1 = Bh + (size_t)(n0 + 64 + srow) * 1024 + scol;
    const int so0 = SWZ(srow, scol);
    const int so1 = SWZ(srow + 64, scol);

    bf16x8 rA0, rA1, rB0, rB1;
    auto load_tiles = [&](int kk) {
        const int ko = kk * 32;
        rA0 = g8(pA0 + ko); rA1 = g8(pA1 + ko);
        rB0 = g8(pB0 + ko); rB1 = g8(pB1 + ko);
    };

    f32x4 acc[4][4];
#pragma unroll
    for (int m = 0; m < 4; ++m)
#pragma unroll
        for (int n = 0; n < 4; ++n) acc[m][n] = (f32x4){0.f, 0.f, 0.f, 0.f};

    const int fr = l & 15;
    const int fk = (l >> 4) * 8;
    const int ar = wr * 64 + fr;
    const int br = wc * 64 + fr;

    load_tiles(0);
    for (int kk = 0; kk < 32; ++kk) {
        __syncthreads();
        *reinterpret_cast<bf16x8*>(&sA[so0]) = rA0;
        *reinterpret_cast<bf16x8*>(&sA[so1]) = rA1;
        *reinterpret_cast<bf16x8*>(&sB[so0]) = rB0;
        *reinterpret_cast<bf16x8*>(&sB[so1]) = rB1;
        __syncthreads();
        if (kk < 31) load_tiles(kk + 1);

        bf16x8 fa[4], fb[4];
#pragma unroll
        for (int m = 0; m < 4; ++m)
            fa[m] = *reinterpret_cast<const bf16x8*>(&sA[SWZ(ar + m * 16, fk)]);
#pragma unroll
        for (int n = 0; n < 4; ++n)
            fb[n] = *reinterpret_cast<const bf16x8*>(&sB[SWZ(br + n * 16, fk)]);
#pragma unroll
        for (int m = 0; m < 4; ++m)
#pragma unroll
            for (int n = 0; n < 4; ++n)
                acc[m][n] = __builtin_amdgcn_mfma_f32_16x16x32_bf16(fa[m], fb[n], acc[m][n], 0, 0, 0);
    }

    const int er4 = (l >> 4) * 4;
    float bvv[4];
#pragma unroll
    for (int n = 0; n < 4; ++n) bvv[n] = bias[n0 + wc * 64 + n * 16 + fr];
#pragma unroll
    for (int m = 0; m < 4; ++m)
#pragma unroll
        for (int n = 0; n < 4; ++n) {
            const int col = n0 + wc * 64 + n * 16 + fr;
            const size_t rb = (size_t)(m0 + wr * 64 + m * 16 + er4) * 1024 + col;
#pragma unroll
            for (int r = 0; r < 4; ++r) C[rb + (size_t)r * 1024] = acc[m][n][r] + bvv[n];
        }
}

// ---------------- flash attention (QBLK=128, fixed-max, exp2, dbuf) -------
// grid flat = 512; XCD swizzle tau=(flat&7)*64+flat/8. Wave w owns 32 q-rows
// (2 fragments). QK^T 1-term; P = exp2(s - 12*log2e); l via ones-MFMA.
// K/V dbuf XOR-swizzled, 1 barrier/tile. Epilogue: wave-private transpose
// through the wave's own dead 8KB K/V buffer (no cross-wave barriers).
#define SM_M2 17.312340490667562f  // 12 * log2(e)

#define ATTN_TILE(SK, SV)                                                      \
  {                                                                            \
    f32x4 s[2][4];                                                             \
    _Pragma("unroll") for (int qm = 0; qm < 2; ++qm)                           \
      _Pragma("unroll") for (int n = 0; n < 4; ++n)                            \
        s[qm][n] = (f32x4){-SM_M2, -SM_M2, -SM_M2, -SM_M2};                    \
    _Pragma("unroll") for (int n = 0; n < 4; ++n)                              \
      _Pragma("unroll") for (int ks = 0; ks < 2; ++ks) {                       \
        bf16x8 bkh = *reinterpret_cast<const bf16x8*>(                         \
            &SK[(n * 16 + fr) * 64 + ((ks * 32 + fk) ^ rswz)]);                \
        _Pragma("unroll") for (int qm = 0; qm < 2; ++qm)                       \
          s[qm][n] = __builtin_amdgcn_mfma_f32_16x16x32_bf16(aqh[qm][ks], bkh, s[qm][n], 0, 0, 0); \
      }                                                                        \
    _Pragma("unroll") for (int qm = 0; qm < 2; ++qm)                           \
      _Pragma("unroll") for (int n = 0; n < 4; ++n)                            \
        _Pragma("unroll") for (int r = 0; r < 4; ++r) {                        \
          const float p = fast_exp2(s[qm][n][r]);                              \
          const int prow = w * 32 + qm * 16 + (l >> 4) * 4 + r;                \
          const int pcol = (n * 16 + (l & 15)) ^ ((prow & 7) << 3);            \
          sPh[prow * 64 + pcol] = f2bf(p);                                     \
        }                                                                      \
    bf16x8 bph[2][2];                                                          \
    _Pragma("unroll") for (int qm = 0; qm < 2; ++qm)                           \
      _Pragma("unroll") for (int ks = 0; ks < 2; ++ks)                         \
        bph[qm][ks] = *reinterpret_cast<const bf16x8*>(                        \
            &sPh[(w * 32 + qm * 16 + fr) * 64 + ((ks * 32 + fk) ^ rswz)]);     \
    _Pragma("unroll") for (int m = 0; m < 4; ++m)                              \
      _Pragma("unroll") for (int ks = 0; ks < 2; ++ks) {                       \
        bf16x8 avh = *reinterpret_cast<const bf16x8*>(                         \
            &SV[(m * 16 + fr) * 64 + ((ks * 32 + fk) ^ rswz)]);                \
        _Pragma("unroll") for (int qm = 0; qm < 2; ++qm)                       \
          aco[qm][m] = __builtin_amdgcn_mfma_f32_16x16x32_bf16(avh, bph[qm][ks], aco[qm][m], 0, 0, 0); \
      }                                                                        \
    _Pragma("unroll") for (int qm = 0; qm < 2; ++qm)                           \
      _Pragma("unroll") for (int ks = 0; ks < 2; ++ks)                         \
        acl[qm] = __builtin_amdgcn_mfma_f32_16x16x32_bf16(vone, bph[qm][ks], acl[qm], 0, 0, 0); \
  }

#define ATTN_STAGE(SK, SV)                                                     \
  {                                                                            \
    _Pragma("unroll") for (int i = 0; i < 2; ++i) {                            \
      *reinterpret_cast<bf16x8*>(&SK[soff[i]]) = rKh[i];                       \
      *reinterpret_cast<bf16x8*>(&SV[soff[i]]) = rVh[i];                       \
    }                                                                          \
  }

__global__ __launch_bounds__(256) void k_attn(
    const u16* __restrict__ Qh,
    const u16* __restrict__ Kh,
    const u16* __restrict__ VTh,
    u16* __restrict__ AOh) {
    __shared__ __attribute__((aligned(16))) u16 sK0[4096];
    __shared__ __attribute__((aligned(16))) u16 sK1[4096];
    __shared__ __attribute__((aligned(16))) u16 sV0[4096];
    __shared__ __attribute__((aligned(16))) u16 sV1[4096];
    __shared__ __attribute__((aligned(16))) u16 sPh[128 * 64];

    const int t = threadIdx.x;
    const int l = t & 63, w = t >> 6;
    const int flat = blockIdx.y * 16 + blockIdx.x;          // 0..511
    const int tau = (flat & 7) * 64 + (flat >> 3);          // bijective
    const int q0 = (tau & 15) * 128;
    const int bh = tau >> 4;
    const int b = bh >> 4, h = bh & 15;
    const size_t qrow0 = (size_t)b * 2048 + q0;

    const u16* Qb_h = Qh + qrow0 * 1024 + h * 64;
    const u16* Kb_h = Kh + (size_t)b * 2048 * 1024 + h * 64;
    const u16* Vb_h = VTh + (size_t)bh * 64 * 2048;

    const int fr = l & 15;
    const int fk = (l >> 4) * 8;

    bf16x8 aqh[2][2];
#pragma unroll
    for (int qm = 0; qm < 2; ++qm)
#pragma unroll
        for (int ks = 0; ks < 2; ++ks) {
            const size_t qo = (size_t)(w * 32 + qm * 16 + fr) * 1024 + ks * 32 + fk;
            aqh[qm][ks] = g8(Qb_h + qo);
        }

    bf16x8 vone;
#pragma unroll
    for (int j = 0; j < 8; ++j) vone[j] = (short)0x3F80;

    f32x4 aco[2][4];
    f32x4 acl[2];
#pragma unroll
    for (int qm = 0; qm < 2; ++qm) {
        acl[qm] = (f32x4){0.f, 0.f, 0.f, 0.f};
#pragma unroll
        for (int m = 0; m < 4; ++m) aco[qm][m] = (f32x4){0.f, 0.f, 0.f, 0.f};
    }

    const int sr = t >> 3, sc = (t & 7) * 8;  // staging: row sr(+32), col sc
    bf16x8 rKh[2], rVh[2];
    auto load_kv = [&](int tt) {
        const int kv0 = tt * 64;
#pragma unroll
        for (int i = 0; i < 2; ++i) {
            const int r2 = sr + i * 32;
            rKh[i] = g8(Kb_h + (size_t)(kv0 + r2) * 1024 + sc);
            rVh[i] = g8(Vb_h + (size_t)r2 * 2048 + kv0 + sc);
        }
    };
    int soff[2];
#pragma unroll
    for (int i = 0; i < 2; ++i) {
        const int r2 = sr + i * 32;
        soff[i] = r2 * 64 + (sc ^ ((r2 & 7) << 3));
    }
    const int rswz = (fr & 7) << 3;

    // prologue: stage tile 0 into buf0
    load_kv(0);
    ATTN_STAGE(sK0, sV0);
    __syncthreads();

    for (int tt = 0; tt < 32; tt += 2) {
        load_kv(tt + 1);
        ATTN_TILE(sK0, sV0);
        ATTN_STAGE(sK1, sV1);
        __syncthreads();
        if (tt + 2 < 32) load_kv(tt + 2);
        ATTN_TILE(sK1, sV1);
        if (tt + 2 < 32) ATTN_STAGE(sK0, sV0);
        __syncthreads();
    }
    // loop's final __syncthreads guarantees all waves finished K/V reads.

#pragma unroll
    for (int qm = 0; qm < 2; ++qm) {
        const float inv = 1.0f / acl[qm][0];
#pragma unroll
        for (int m = 0; m < 4; ++m) aco[qm][m] *= inv;
    }

    // wave-private transpose: wave w uses its own dead 8KB buffer as a
    // swizzled [32][64] fp32 region; no cross-wave sharing -> no barriers.
    float* Ol = reinterpret_cast<float*>(
        (w == 0) ? sK0 : (w == 1) ? sK1 : (w == 2) ? sV0 : sV1);
#pragma unroll
    for (int qm = 0; qm < 2; ++qm) {
        const int qr = qm * 16 + (l & 15);
        const int sw = (qr & 7) << 3;
#pragma unroll
        for (int m = 0; m < 4; ++m)
#pragma unroll
            for (int r = 0; r < 4; ++r)
                Ol[qr * 64 + ((m * 16 + (l >> 4) * 4 + r) ^ sw)] = aco[qm][m][r];
    }
#pragma unroll
    for (int it = 0; it < 4; ++it) {
        const int qr = (l >> 3) + it * 8;   // 0..31 within the wave's rows
        const int cb = (l & 7) * 8;
        const int sw = (qr & 7) << 3;
        const float* srcp = &Ol[qr * 64 + (cb ^ sw)];
        u16x8 oh;
#pragma unroll
        for (int j = 0; j < 8; ++j) oh[j] = f2bf(srcp[j]);
        const size_t ob = (qrow0 + w * 32 + qr) * 1024 + h * 64 + cb;
        *reinterpret_cast<u16x8*>(&AOh[ob]) = oh;
    }
}

// ---------------- host ----------------
extern "C" void kernel_launch(void* const* d_in, const int* in_sizes, int n_in,
                              void* d_out, int out_size, void* d_ws, size_t ws_size,
                              hipStream_t stream) {
    const float* q = (const float*)d_in[0];
    const float* k = (const float*)d_in[1];
    const float* v = (const float*)d_in[2];
    const float* Wq = (const float*)d_in[3];
    const float* bq = (const float*)d_in[4];
    const float* Wk = (const float*)d_in[5];
    const float* bk = (const float*)d_in[6];
    const float* Wv = (const float*)d_in[7];
    const float* bv = (const float*)d_in[8];
    const float* Wo = (const float*)d_in[9];
    const float* bo = (const float*)d_in[10];
    const float* phase = (const float*)d_in[11];
    float* out = (float*)d_out;

    char* ws = (char*)d_ws;
    const size_t MB = 1u << 20;
    u16* Wq_h = (u16*)(ws + 0 * MB);
    u16* Wk_h = (u16*)(ws + 2 * MB);
    u16* Wv_h = (u16*)(ws + 4 * MB);
    u16* Wo_h = (u16*)(ws + 6 * MB);
    u16* QR_h = (u16*)(ws + 64 * MB);
    u16* KR_h = (u16*)(ws + 80 * MB);
    u16* VT_h = (u16*)(ws + 96 * MB);
    u16* AO_h = (u16*)(ws + 16 * MB);

    // 1. weight split (small)
    k_splitW<<<dim3(1024, 4), 256, 0, stream>>>(Wq, Wk, Wv, Wo,
                                                Wq_h, Wk_h, Wv_h, Wo_h);
    // 2. fused QKV projections (z=0,1,2); A staged from fp32 with in-reg cvt
    k_gemm<<<dim3(8, 32, 3), 256, 0, stream>>>(
        q, k, v, Wq_h, Wk_h, Wv_h,
        bq, bk, bv, phase, QR_h, KR_h, VT_h);
    // 3. attention (QBLK=128)
    k_attn<<<dim3(16, 32), 256, 0, stream>>>(QR_h, KR_h, VT_h, AO_h);
    // 4. output projection (1-term)
    k_gemm1<<<dim3(8, 32), 256, 0, stream>>>(AO_h, Wo_h, bo, out);
    (void)in_sizes; (void)n_in; (void)out_size; (void)ws_size;
}